// Round 17
// baseline (152.492 us; speedup 1.0000x reference)
//
#include <hip/hip_runtime.h>

typedef unsigned short u16;
typedef unsigned int u32;
using bf16x8 = __attribute__((ext_vector_type(8))) __bf16;
using u16x8  = __attribute__((ext_vector_type(8))) u16;
using f32x4  = __attribute__((ext_vector_type(4))) float;

#define SEQn   2048
#define DMn    1024
#define NHn    16
#define DKn    64
#define BATCHn 2
#define MR     (BATCHn*SEQn)   // 4096 rows

#define SSCALE 0.18033688f     // 1/sqrt(64) * log2(e)
#define DEFER_RAW 63.77f       // 11.5 log2-units in raw-score units

__device__ __forceinline__ u16 f2bf(float f){
  u32 u = __builtin_bit_cast(u32, f);
  u32 r = (u + 0x7FFFu + ((u >> 16) & 1u)) >> 16;   // RNE
  return (u16)r;
}
__device__ __forceinline__ float bf2f(u32 b){ return __builtin_bit_cast(float, b << 16); }

// async global->LDS, 16B per lane (linear dest = wave base + lane*16)
__device__ __forceinline__ void gload16(const void* g, void* l){
  __builtin_amdgcn_global_load_lds((const __attribute__((address_space(1))) unsigned int*)g,
                                   (__attribute__((address_space(3))) unsigned int*)l, 16, 0, 0);
}

// ---------------- fused prep: f32->bf16 converts + RoPE table (one launch) ----------------
__global__ __launch_bounds__(256) void prep_all(const float* __restrict__ Q, const float* __restrict__ K,
                                                const float* __restrict__ V,
                                                const float* __restrict__ w0, const float* __restrict__ w1,
                                                const float* __restrict__ w2, const float* __restrict__ w3,
                                                u16* __restrict__ dQ, u16* __restrict__ dK, u16* __restrict__ dV,
                                                u16* __restrict__ dw0, u16* __restrict__ dw1,
                                                u16* __restrict__ dw2, u16* __restrict__ dw3,
                                                const int* __restrict__ pos, float2* __restrict__ tab){
  const int y = blockIdx.y;
  const int i = blockIdx.x*256 + threadIdx.x;
  if (y == 7){
    if (i >= SEQn*32) return;
    int s = i >> 5, k = i & 31;
    float inv = powf(10000.0f, -(float)k * (1.0f/32.0f));
    float a = (float)pos[s] * inv;
    float sn, cs;
    sincosf(a, &sn, &cs);
    tab[i] = make_float2(cs, sn);
    return;
  }
  const float* s; u16* d;
  if      (y == 0){ s = Q;  d = dQ;  }
  else if (y == 1){ s = K;  d = dK;  }
  else if (y == 2){ s = V;  d = dV;  }
  else {
    if (i >= (DMn*DMn)/4) return;
    s = (y == 3) ? w0 : (y == 4) ? w1 : (y == 5) ? w2 : w3;
    d = (y == 3) ? dw0 : (y == 4) ? dw1 : (y == 5) ? dw2 : dw3;
  }
  float4 v = ((const float4*)s)[i];
  ushort4 o = { f2bf(v.x), f2bf(v.y), f2bf(v.z), f2bf(v.w) };
  ((ushort4*)d)[i] = o;
}

// ---------------- RoPE in place (fallback path only) ----------------
__global__ __launch_bounds__(256) void rope2_kernel(u32* __restrict__ xq, u32* __restrict__ xk,
                                                    const int* __restrict__ pos){
  u32* x = blockIdx.y ? xk : xq;
  int p = blockIdx.x*256 + threadIdx.x;
  int s = (p >> 9) & (SEQn - 1);
  int k = p & 31;
  float inv = powf(10000.0f, -(float)k * (1.0f/32.0f));
  float a = (float)pos[s] * inv;
  float sn, cs;
  sincosf(a, &sn, &cs);
  u32 u = x[p];
  float xe = bf2f(u & 0xffffu);
  float xo = bf2f(u >> 16);
  float re = xe*cs - xo*sn;
  float ro = xe*sn + xo*cs;
  x[p] = (u32)f2bf(re) | ((u32)f2bf(ro) << 16);
}

// ---------------- bf16 MFMA GEMM, m97 structure: C = A * B^T ----------------
template<typename CT>
__device__ __forceinline__ void gemm_bb_body(const u16* __restrict__ A, const u16* __restrict__ B,
                                             CT* __restrict__ C, int bx, int by, bool tv,
                                             const float2* __restrict__ tab){
  __shared__ u16 As[128*64];
  __shared__ u16 Bs[128*64];
  const int tid = threadIdx.x, lane = tid & 63, w = tid >> 6;
  const int m0 = by*128, n0 = bx*128;
  const int wr = (w >> 1)*64, wc = (w & 1)*64;
  const int l15 = lane & 15, lg = lane >> 4;
  f32x4 acc[4][4];
#pragma unroll
  for (int i = 0; i < 4; i++)
#pragma unroll
    for (int j = 0; j < 4; j++) acc[i][j] = (f32x4){0.f,0.f,0.f,0.f};

  for (int kt = 0; kt < DMn; kt += 64){
    __syncthreads();
#pragma unroll
    for (int i = 0; i < 4; i++){
      const int c = i*256 + tid, row = c >> 3, cc = c & 7;
      gload16(A + (size_t)(m0 + row)*DMn + kt + ((cc ^ (row&7))<<3), &As[(size_t)c<<3]);
    }
#pragma unroll
    for (int i = 0; i < 4; i++){
      const int c = i*256 + tid, row = c >> 3, cc = c & 7;
      gload16(B + (size_t)(n0 + row)*DMn + kt + ((cc ^ (row&7))<<3), &Bs[(size_t)c<<3]);
    }
    __syncthreads();

#pragma unroll
    for (int kk = 0; kk < 2; kk++){
      bf16x8 af[4], bfr[4];
      const int ch = kk*4 + lg;
#pragma unroll
      for (int i = 0; i < 4; i++){
        const int row = wr + i*16 + l15;
        af[i] = *(const bf16x8*)&As[row*64 + ((ch ^ (row&7))<<3)];
      }
#pragma unroll
      for (int j = 0; j < 4; j++){
        const int col = wc + j*16 + l15;
        bfr[j] = *(const bf16x8*)&Bs[col*64 + ((ch ^ (col&7))<<3)];
      }
#pragma unroll
      for (int i = 0; i < 4; i++)
#pragma unroll
        for (int j = 0; j < 4; j++)
          acc[i][j] = __builtin_amdgcn_mfma_f32_16x16x32_bf16(af[i], bfr[j], acc[i][j], 0, 0, 0);
    }
  }

  if (tv){
#pragma unroll
    for (int i = 0; i < 4; i++)
#pragma unroll
      for (int j = 0; j < 4; j++){
        const int row = m0 + wr + i*16 + lg*4;
        const int col = n0 + wc + j*16 + l15;
        ushort4 o = { f2bf(acc[i][j][0]), f2bf(acc[i][j][1]), f2bf(acc[i][j][2]), f2bf(acc[i][j][3]) };
        *(ushort4*)((u16*)C + (size_t)(((row>>11)<<10) + col)*SEQn + (row & (SEQn-1))) = o;
      }
    return;
  }
  if constexpr (sizeof(CT) == 2){
    if (tab){        // fused RoPE epilogue (Q/K projections)
#pragma unroll
      for (int i = 0; i < 4; i++)
#pragma unroll
        for (int j = 0; j < 4; j++){
          const int col = n0 + wc + j*16 + l15;
          const int k = (col & 63) >> 1;
          const float sgn = (col & 1) ? 1.0f : -1.0f;
#pragma unroll
          for (int r = 0; r < 4; r++){
            const int row = m0 + wr + i*16 + lg*4 + r;
            const int s = row & (SEQn - 1);
            float x = acc[i][j][r];
            float p = __shfl_xor(x, 1);
            float2 cs = tab[(s << 5) | k];
            C[(size_t)row*DMn + col] = f2bf(fmaf(x, cs.x, sgn * p * cs.y));
          }
        }
      return;
    }
  }
#pragma unroll
  for (int i = 0; i < 4; i++)
#pragma unroll
    for (int j = 0; j < 4; j++)
#pragma unroll
      for (int r = 0; r < 4; r++){
        const int row = m0 + wr + i*16 + lg*4 + r;
        const int col = n0 + wc + j*16 + l15;
        if constexpr (sizeof(CT) == 2) C[(size_t)row*DMn + col] = f2bf(acc[i][j][r]);
        else                           C[(size_t)row*DMn + col] = acc[i][j][r];
      }
}

__global__ __launch_bounds__(256) void gemm_qkv_bb(const u16* A0, const u16* A1, const u16* A2,
                                                   const u16* W0, const u16* W1, const u16* W2,
                                                   u16* C0, u16* C1, u16* C2,
                                                   const float2* tab){
  const int z = blockIdx.z;
  const u16* A = (z == 0) ? A0 : (z == 1) ? A1 : A2;
  const u16* W = (z == 0) ? W0 : (z == 1) ? W1 : W2;
  u16*       C = (z == 0) ? C0 : (z == 1) ? C1 : C2;
  gemm_bb_body<u16>(A, W, C, blockIdx.x, blockIdx.y, z == 2, (z < 2) ? tab : nullptr);
}
__global__ __launch_bounds__(256) void gemm_out_bb(const u16* A, const u16* W, float* C){
  gemm_bb_body<float>(A, W, C, blockIdx.x, blockIdx.y, false, nullptr);
}

// ---------------- FALLBACK f32-input GEMM ----------------
template<typename AT, typename CT>
__device__ __forceinline__ void gemm_body(const AT* __restrict__ A, const float* __restrict__ W,
                                          CT* __restrict__ C, int bx, int by, bool tv){
  __shared__ u16 As[128*64];
  __shared__ u16 Bs[128*64];
  const int tid = threadIdx.x, lane = tid & 63, w = tid >> 6;
  const int m0 = by*128, n0 = bx*128;
  const int wr = (w >> 1)*64, wc = (w & 1)*64;
  const int l15 = lane & 15, lg = lane >> 4;
  f32x4 acc[4][4];
#pragma unroll
  for (int i = 0; i < 4; i++)
#pragma unroll
    for (int j = 0; j < 4; j++) acc[i][j] = (f32x4){0.f,0.f,0.f,0.f};

  for (int kt = 0; kt < DMn; kt += 64){
    float4 wv[8];
#pragma unroll
    for (int it = 0; it < 8; it++){
      const int f = it*256 + tid, row = f >> 4, c4 = f & 15;
      wv[it] = *(const float4*)(W + (size_t)(n0 + row)*DMn + kt + c4*4);
    }
    if constexpr (sizeof(AT) == 4){
      float4 av[8];
#pragma unroll
      for (int it = 0; it < 8; it++){
        const int f = it*256 + tid, row = f >> 4, c4 = f & 15;
        av[it] = *(const float4*)((const float*)A + (size_t)(m0 + row)*DMn + kt + c4*4);
      }
      __syncthreads();
#pragma unroll
      for (int it = 0; it < 8; it++){
        const int f = it*256 + tid, row = f >> 4, c4 = f & 15;
        ushort4 o = { f2bf(av[it].x), f2bf(av[it].y), f2bf(av[it].z), f2bf(av[it].w) };
        *(ushort4*)&As[row*64 + (((c4>>1) ^ (row&7))<<3) + ((c4&1)<<2)] = o;
      }
    } else {
      uint4 av4[4];
#pragma unroll
      for (int it = 0; it < 4; it++){
        const int f = it*256 + tid, row = f >> 3, ch = f & 7;
        av4[it] = *(const uint4*)((const u16*)A + (size_t)(m0 + row)*DMn + kt + ch*8);
      }
      __syncthreads();
#pragma unroll
      for (int it = 0; it < 4; it++){
        const int f = it*256 + tid, row = f >> 3, ch = f & 7;
        *(uint4*)&As[row*64 + ((ch ^ (row&7))<<3)] = av4[it];
      }
    }
#pragma unroll
    for (int it = 0; it < 8; it++){
      const int f = it*256 + tid, row = f >> 4, c4 = f & 15;
      ushort4 o = { f2bf(wv[it].x), f2bf(wv[it].y), f2bf(wv[it].z), f2bf(wv[it].w) };
      *(ushort4*)&Bs[row*64 + (((c4>>1) ^ (row&7))<<3) + ((c4&1)<<2)] = o;
    }
    __syncthreads();

#pragma unroll
    for (int kk = 0; kk < 2; kk++){
      bf16x8 af[4], bfr[4];
      const int ch = kk*4 + lg;
#pragma unroll
      for (int i = 0; i < 4; i++){
        const int row = wr + i*16 + l15;
        af[i] = *(const bf16x8*)&As[row*64 + ((ch ^ (row&7))<<3)];
      }
#pragma unroll
      for (int j = 0; j < 4; j++){
        const int col = wc + j*16 + l15;
        bfr[j] = *(const bf16x8*)&Bs[col*64 + ((ch ^ (col&7))<<3)];
      }
#pragma unroll
      for (int i = 0; i < 4; i++)
#pragma unroll
        for (int j = 0; j < 4; j++)
          acc[i][j] = __builtin_amdgcn_mfma_f32_16x16x32_bf16(af[i], bfr[j], acc[i][j], 0, 0, 0);
    }
    __syncthreads();
  }

  if (tv){
#pragma unroll
    for (int i = 0; i < 4; i++)
#pragma unroll
      for (int j = 0; j < 4; j++){
        const int row = m0 + wr + i*16 + lg*4;
        const int col = n0 + wc + j*16 + l15;
        ushort4 o = { f2bf(acc[i][j][0]), f2bf(acc[i][j][1]), f2bf(acc[i][j][2]), f2bf(acc[i][j][3]) };
        *(ushort4*)((u16*)C + (size_t)(((row>>11)<<10) + col)*SEQn + (row & (SEQn-1))) = o;
      }
  } else {
#pragma unroll
    for (int i = 0; i < 4; i++)
#pragma unroll
      for (int j = 0; j < 4; j++)
#pragma unroll
        for (int r = 0; r < 4; r++){
          const int row = m0 + wr + i*16 + lg*4 + r;
          const int col = n0 + wc + j*16 + l15;
          if constexpr (sizeof(CT) == 2) C[(size_t)row*DMn + col] = f2bf(acc[i][j][r]);
          else                           C[(size_t)row*DMn + col] = acc[i][j][r];
        }
  }
}

__global__ __launch_bounds__(256) void gemm_qkv(const float* A0, const float* A1, const float* A2,
                                                const float* W0, const float* W1, const float* W2,
                                                u16* C0, u16* C1, u16* C2){
  const int z = blockIdx.z;
  const float* A = (z == 0) ? A0 : (z == 1) ? A1 : A2;
  const float* W = (z == 0) ? W0 : (z == 1) ? W1 : W2;
  u16*         C = (z == 0) ? C0 : (z == 1) ? C1 : C2;
  gemm_body<float, u16>(A, W, C, blockIdx.x, blockIdx.y, z == 2);
}
__global__ __launch_bounds__(256) void gemm_out(const u16* A, const float* W, float* C){
  gemm_body<u16, float>(A, W, C, blockIdx.x, blockIdx.y, false);
}

// ---------------- MFMA causal flash attention ----------------
// Round-17: K-loop unrolled 2x -> COMPILE-TIME buffer parity. All LDS addresses
// are loop-invariant regs + immediates; staging pointers advance by constant
// strides. Arithmetic identical to round 16.
__device__ __forceinline__ void attn_tile(int t, int qt, int qw, int l15, int lg, int tid,
                                          const u16* __restrict__ Kc, const u16* __restrict__ Vc,
                                          u16* __restrict__ Kn, u16* __restrict__ Vn,
                                          u16* __restrict__ Plw,
                                          const bf16x8 qf0, const bf16x8 qf1, const bf16x8 onesf,
                                          const u16*& kstage, const u16*& vstage,
                                          float* __restrict__ mrow, float* __restrict__ lrow,
                                          f32x4* __restrict__ accO){
  const int kt = t*64;
  if (t < qt){                               // async prefetch of tile t+1 into (Kn,Vn)
    gload16(kstage,           Kn + (size_t)tid*8);
    gload16(kstage + 32*DMn,  Kn + 2048 + (size_t)tid*8);
    gload16(vstage,           Vn + (size_t)tid*8);
    gload16(vstage + 32*SEQn, Vn + 2048 + (size_t)tid*8);
    kstage += 64*DMn;
    vstage += 64;
  }

  f32x4 sc[4];
  __builtin_amdgcn_s_setprio(1);
#pragma unroll
  for (int f = 0; f < 4; f++){
    const int n = 16*f + l15;
    bf16x8 kb0 = *(const bf16x8*)&Kc[n*64 + (( lg    ^ (n&7))<<3)];
    bf16x8 kb1 = *(const bf16x8*)&Kc[n*64 + (((lg+4) ^ (n&7))<<3)];
    f32x4 z = (f32x4){0.f,0.f,0.f,0.f};
    z = __builtin_amdgcn_mfma_f32_16x16x32_bf16(qf0, kb0, z, 0, 0, 0);
    z = __builtin_amdgcn_mfma_f32_16x16x32_bf16(qf1, kb1, z, 0, 0, 0);
    sc[f] = z;
  }
  __builtin_amdgcn_s_setprio(0);

  // ---- mask (diagonal tile only) + LANE-LOCAL row max ----
  const bool needmask = (kt + 63 > qw);
  float mx[4];
#pragma unroll
  for (int r = 0; r < 4; r++){
    float v0 = sc[0][r], v1 = sc[1][r], v2 = sc[2][r], v3 = sc[3][r];
    if (needmask){
      const int qg = qw + lg*4 + r;
      if (kt +      l15 > qg) v0 = -3e38f;
      if (kt + 16 + l15 > qg) v1 = -3e38f;
      if (kt + 32 + l15 > qg) v2 = -3e38f;
      if (kt + 48 + l15 > qg) v3 = -3e38f;
      sc[0][r]=v0; sc[1][r]=v1; sc[2][r]=v2; sc[3][r]=v3;
    }
    mx[r] = fmaxf(fmaxf(v0,v1), fmaxf(v2,v3));
  }
  // ---- defer-max check via __all over lane-local maxes ----
  const float dm = fmaxf(fmaxf(mx[0]-mrow[0], mx[1]-mrow[1]),
                         fmaxf(mx[2]-mrow[2], mx[3]-mrow[3]));
  if (!__all(dm <= DEFER_RAW)){
#pragma unroll
    for (int r = 0; r < 4; r++){
      float v = mx[r];
      v = fmaxf(v, __shfl_xor(v, 1));
      v = fmaxf(v, __shfl_xor(v, 2));
      v = fmaxf(v, __shfl_xor(v, 4));
      v = fmaxf(v, __shfl_xor(v, 8));
      const float mn = fmaxf(mrow[r], v);
      const float corr = exp2f((mrow[r] - mn)*SSCALE);
      mrow[r] = mn;
      lrow[r] *= corr;
      accO[0][r] *= corr; accO[1][r] *= corr; accO[2][r] *= corr; accO[3][r] *= corr;
    }
  }
  // ---- P = exp2(fma(S,S,-mS)) -> full-width Pl [16 q][64 k] ----
#pragma unroll
  for (int r = 0; r < 4; r++){
    const float ms = -mrow[r]*SSCALE;
    const float p0 = exp2f(fmaf(sc[0][r], SSCALE, ms));
    const float p1 = exp2f(fmaf(sc[1][r], SSCALE, ms));
    const float p2 = exp2f(fmaf(sc[2][r], SSCALE, ms));
    const float p3 = exp2f(fmaf(sc[3][r], SSCALE, ms));
    u32 pk01, pk23;
    asm("v_cvt_pk_bf16_f32 %0, %1, %2" : "=v"(pk01) : "v"(p0), "v"(p1));
    asm("v_cvt_pk_bf16_f32 %0, %1, %2" : "=v"(pk23) : "v"(p2), "v"(p3));
    const int q = lg*4 + r, qb = q*64, qx = q&7;
    const int k0 = l15, k1 = 16+l15, k2 = 32+l15, k3 = 48+l15;
    Plw[qb + (((k0>>3) ^ qx)<<3) + (k0&7)] = (u16)(pk01 & 0xffffu);
    Plw[qb + (((k1>>3) ^ qx)<<3) + (k1&7)] = (u16)(pk01 >> 16);
    Plw[qb + (((k2>>3) ^ qx)<<3) + (k2&7)] = (u16)(pk23 & 0xffffu);
    Plw[qb + (((k3>>3) ^ qx)<<3) + (k3&7)] = (u16)(pk23 >> 16);
  }
  // ---- O += P V; l += P·1 via ones-B MFMA ----
  f32x4 lsum = (f32x4){0.f,0.f,0.f,0.f};
  __builtin_amdgcn_s_setprio(1);
#pragma unroll
  for (int ks = 0; ks < 2; ks++){
    bf16x8 pa = *(const bf16x8*)&Plw[ l15*64 + (((4*ks + lg) ^ (l15&7))<<3) ];
    lsum = __builtin_amdgcn_mfma_f32_16x16x32_bf16(pa, onesf, lsum, 0, 0, 0);
#pragma unroll
    for (int df = 0; df < 4; df++){
      const int d = 16*df + l15;
      bf16x8 vb = *(const bf16x8*)&Vc[ d*64 + (((4*ks + lg) ^ (d&7))<<3) ];
      accO[df] = __builtin_amdgcn_mfma_f32_16x16x32_bf16(pa, vb, accO[df], 0, 0, 0);
    }
  }
  __builtin_amdgcn_s_setprio(0);
#pragma unroll
  for (int r = 0; r < 4; r++) lrow[r] += lsum[r];

  __syncthreads();   // fences buf reads AND drains prefetched gloads
}

__device__ __forceinline__ void attn_phase(const u16* __restrict__ xq, const u16* __restrict__ xk,
                                           const u16* __restrict__ xvT, u16* __restrict__ xo,
                                           u16* __restrict__ Kl0, u16* __restrict__ Kl1,
                                           u16* __restrict__ Vl0, u16* __restrict__ Vl1,
                                           u16* __restrict__ Plw, size_t bhbase, size_t vtbase,
                                           int qt, int tid){
  const int lane = tid & 63, w = tid >> 6;
  const int l15 = lane & 15, lg = lane >> 4;
  const int qw = qt*64 + w*16;

  const u16* qptr = xq + bhbase + (size_t)(qw + l15)*DMn + lg*8;
  const bf16x8 qf0 = *(const bf16x8*)(qptr);
  const bf16x8 qf1 = *(const bf16x8*)(qptr + 32);

  const u16x8 ou = {0x3F80,0x3F80,0x3F80,0x3F80,0x3F80,0x3F80,0x3F80,0x3F80};
  const bf16x8 onesf = __builtin_bit_cast(bf16x8, ou);

  float mrow[4], lrow[4];
  f32x4 accO[4];
#pragma unroll
  for (int r = 0; r < 4; r++){ mrow[r] = 0.f; lrow[r] = 0.f; }
#pragma unroll
  for (int df = 0; df < 4; df++) accO[df] = (f32x4){0.f,0.f,0.f,0.f};

  // per-thread staging bases (advance by constant strides)
  const int srow = tid >> 3, schk = tid & 7;
  const int sswz = (schk ^ (srow & 7)) << 3;
  const u16* kstage = xk  + bhbase + (size_t)srow*DMn  + sswz;
  const u16* vstage = xvT + vtbase + (size_t)srow*SEQn + sswz;

  // stage tile 0
  gload16(kstage,           Kl0 + (size_t)tid*8);
  gload16(kstage + 32*DMn,  Kl0 + 2048 + (size_t)tid*8);
  gload16(vstage,           Vl0 + (size_t)tid*8);
  gload16(vstage + 32*SEQn, Vl0 + 2048 + (size_t)tid*8);
  kstage += 64*DMn;
  vstage += 64;
  __syncthreads();

  int t = 0;
  for (;;){
    attn_tile(t, qt, qw, l15, lg, tid, Kl0, Vl0, Kl1, Vl1, Plw, qf0, qf1, onesf,
              kstage, vstage, mrow, lrow, accO);
    if (++t > qt) break;
    attn_tile(t, qt, qw, l15, lg, tid, Kl1, Vl1, Kl0, Vl0, Plw, qf0, qf1, onesf,
              kstage, vstage, mrow, lrow, accO);
    if (++t > qt) break;
  }

#pragma unroll
  for (int r = 0; r < 4; r++){
    const float inv = 1.0f / lrow[r];
    const int qg = qw + lg*4 + r;
    u16* dst = xo + bhbase + (size_t)qg*DMn;
#pragma unroll
    for (int df = 0; df < 4; df++)
      dst[16*df + l15] = f2bf(accO[df][r] * inv);
  }
}

// 1024 blocks: orig = [slot:2][qtB:3][bh:5]. Co-resident quad shares bh
// (K/V stream L2-shared, XCD = bh%8) with qt quad {qtB,31-qtB,8+qtB,23-qtB}
// -> exactly 66 tiles per CU. LDS 40KB -> 4 blocks/CU.
__global__ __launch_bounds__(256) void attn_mfma(const u16* __restrict__ xq, const u16* __restrict__ xk,
                                                 const u16* __restrict__ xvT, u16* __restrict__ xo){
  __shared__ u16 Kl[2][64*64];
  __shared__ u16 Vl[2][64*64];
  __shared__ u16 Pl[4][16*64];
  const int tid = threadIdx.x;
  const int orig = blockIdx.x;
  const int bh  = orig & 31;
  const int qtB = (orig >> 5) & 7;
  const int s   = orig >> 8;
  const int qt  = (s == 0) ? qtB : (s == 1) ? 31 - qtB : (s == 2) ? 8 + qtB : 23 - qtB;
  const int b = bh >> 4, h = bh & 15;
  const size_t bhbase = (size_t)b*SEQn*DMn + (size_t)h*DKn;
  const size_t vtbase = ((size_t)b*1024 + (size_t)h*64)*SEQn;
  u16* Plw = &Pl[tid >> 6][0];

  attn_phase(xq, xk, xvT, xo, &Kl[0][0], &Kl[1][0], &Vl[0][0], &Vl[1][0], Plw, bhbase, vtbase, qt, tid);
}

extern "C" void kernel_launch(void* const* d_in, const int* in_sizes, int n_in,
                              void* d_out, int out_size, void* d_ws, size_t ws_size,
                              hipStream_t stream){
  (void)in_sizes; (void)n_in;
  const float* Q  = (const float*)d_in[0];
  const float* K  = (const float*)d_in[1];
  const float* V  = (const float*)d_in[2];
  const int*  pos = (const int*)  d_in[3];
  const float* wq = (const float*)d_in[4];
  const float* wk = (const float*)d_in[5];
  const float* wv = (const float*)d_in[6];
  const float* wo = (const float*)d_in[7];

  const size_t SZ  = (size_t)MR*DMn;         // 4,194,304 elements
  const size_t TB  = SZ*2;                   // 8 MB per bf16 tensor
  const size_t WSZ = (size_t)DMn*DMn;
  const size_t WB  = WSZ*2;                  // 2 MB per bf16 weight
  const size_t TABB = (size_t)SEQn*32*8;     // 512 KB cos/sin table

  if (ws_size >= 6*TB + 4*WB + TABB){
    // ---- fast path: fused prep + gload_lds GEMMs + fused-RoPE epilogue ----
    char* w = (char*)d_ws;
    u16* bQ  = (u16*)(w);                    // reused as xo after gemm_qkv_bb
    u16* bK  = (u16*)(w + TB);
    u16* bV  = (u16*)(w + 2*TB);
    u16* bwq = (u16*)(w + 3*TB);
    u16* bwk = (u16*)(w + 3*TB + WB);
    u16* bwv = (u16*)(w + 3*TB + 2*WB);
    u16* bwo = (u16*)(w + 3*TB + 3*WB);
    u16* xq  = (u16*)(w + 3*TB + 4*WB);
    u16* xk  = (u16*)(w + 4*TB + 4*WB);
    u16* xvT = (u16*)(w + 5*TB + 4*WB);      // [b][h][d][s]
    float2* tab = (float2*)(w + 6*TB + 4*WB);
    u16* xo  = bQ;

    dim3 pg((int)(SZ/4/256), 8);             // (4096, 8)
    prep_all<<<pg, 256, 0, stream>>>(Q, K, V, wq, wk, wv, wo,
                                     bQ, bK, bV, bwq, bwk, bwv, bwo, pos, tab);

    dim3 gg(DMn/128, MR/128, 3);
    gemm_qkv_bb<<<gg, 256, 0, stream>>>(bQ, bK, bV, bwq, bwk, bwv, xq, xk, xvT, tab);

    attn_mfma<<<1024, 256, 0, stream>>>(xq, xk, xvT, xo);

    dim3 go(DMn/128, MR/128);
    gemm_out_bb<<<go, 256, 0, stream>>>(xo, bwo, (float*)d_out);
  } else if (ws_size >= 4*TB){
    // ---- fallback: f32-input GEMMs + separate RoPE ----
    char* w = (char*)d_ws;
    u16* xq  = (u16*)(w);
    u16* xk  = (u16*)(w + TB);
    u16* xvT = (u16*)(w + 2*TB);
    u16* xo  = (u16*)(w + 3*TB);

    dim3 gg(DMn/128, MR/128, 3);
    gemm_qkv<<<gg, 256, 0, stream>>>(Q, K, V, wq, wk, wv, xq, xk, xvT);
    dim3 rg((int)(SZ/2/256), 2);
    rope2_kernel<<<rg, 256, 0, stream>>>((u32*)xq, (u32*)xk, pos);
    attn_mfma<<<1024, 256, 0, stream>>>(xq, xk, xvT, xo);
    dim3 go(DMn/128, MR/128);
    gemm_out<<<go, 256, 0, stream>>>(xo, wo, (float*)d_out);
  } else {
    hipMemsetAsync(d_out, 0x42, (size_t)out_size*4, stream);
  }
}

// Round 18
// 141.389 us; speedup vs baseline: 1.0785x; 1.0785x over previous
//
#include <hip/hip_runtime.h>

typedef unsigned short u16;
typedef unsigned int u32;
using bf16x8 = __attribute__((ext_vector_type(8))) __bf16;
using u16x8  = __attribute__((ext_vector_type(8))) u16;
using f32x4  = __attribute__((ext_vector_type(4))) float;

#define SEQn   2048
#define DMn    1024
#define NHn    16
#define DKn    64
#define BATCHn 2
#define MR     (BATCHn*SEQn)   // 4096 rows

#define SSCALE 0.18033688f     // 1/sqrt(64) * log2(e)
#define DEFER_RAW 63.77f       // 11.5 log2-units in raw-score units

__device__ __forceinline__ u16 f2bf(float f){
  u32 u = __builtin_bit_cast(u32, f);
  u32 r = (u + 0x7FFFu + ((u >> 16) & 1u)) >> 16;   // RNE
  return (u16)r;
}
__device__ __forceinline__ float bf2f(u32 b){ return __builtin_bit_cast(float, b << 16); }

// async global->LDS, 16B per lane (linear dest = wave base + lane*16)
__device__ __forceinline__ void gload16(const void* g, void* l){
  __builtin_amdgcn_global_load_lds((const __attribute__((address_space(1))) unsigned int*)g,
                                   (__attribute__((address_space(3))) unsigned int*)l, 16, 0, 0);
}

// ---------------- fused prep: f32->bf16 converts + RoPE table (one launch) ----------------
__global__ __launch_bounds__(256) void prep_all(const float* __restrict__ Q, const float* __restrict__ K,
                                                const float* __restrict__ V,
                                                const float* __restrict__ w0, const float* __restrict__ w1,
                                                const float* __restrict__ w2, const float* __restrict__ w3,
                                                u16* __restrict__ dQ, u16* __restrict__ dK, u16* __restrict__ dV,
                                                u16* __restrict__ dw0, u16* __restrict__ dw1,
                                                u16* __restrict__ dw2, u16* __restrict__ dw3,
                                                const int* __restrict__ pos, float2* __restrict__ tab){
  const int y = blockIdx.y;
  const int i = blockIdx.x*256 + threadIdx.x;
  if (y == 7){
    if (i >= SEQn*32) return;
    int s = i >> 5, k = i & 31;
    float inv = powf(10000.0f, -(float)k * (1.0f/32.0f));
    float a = (float)pos[s] * inv;
    float sn, cs;
    sincosf(a, &sn, &cs);
    tab[i] = make_float2(cs, sn);
    return;
  }
  const float* s; u16* d;
  if      (y == 0){ s = Q;  d = dQ;  }
  else if (y == 1){ s = K;  d = dK;  }
  else if (y == 2){ s = V;  d = dV;  }
  else {
    if (i >= (DMn*DMn)/4) return;
    s = (y == 3) ? w0 : (y == 4) ? w1 : (y == 5) ? w2 : w3;
    d = (y == 3) ? dw0 : (y == 4) ? dw1 : (y == 5) ? dw2 : dw3;
  }
  float4 v = ((const float4*)s)[i];
  ushort4 o = { f2bf(v.x), f2bf(v.y), f2bf(v.z), f2bf(v.w) };
  ((ushort4*)d)[i] = o;
}

// ---------------- RoPE in place (fallback path only) ----------------
__global__ __launch_bounds__(256) void rope2_kernel(u32* __restrict__ xq, u32* __restrict__ xk,
                                                    const int* __restrict__ pos){
  u32* x = blockIdx.y ? xk : xq;
  int p = blockIdx.x*256 + threadIdx.x;
  int s = (p >> 9) & (SEQn - 1);
  int k = p & 31;
  float inv = powf(10000.0f, -(float)k * (1.0f/32.0f));
  float a = (float)pos[s] * inv;
  float sn, cs;
  sincosf(a, &sn, &cs);
  u32 u = x[p];
  float xe = bf2f(u & 0xffffu);
  float xo = bf2f(u >> 16);
  float re = xe*cs - xo*sn;
  float ro = xe*sn + xo*cs;
  x[p] = (u32)f2bf(re) | ((u32)f2bf(ro) << 16);
}

// ---------------- bf16 MFMA GEMM, m97 structure: C = A * B^T ----------------
template<typename CT>
__device__ __forceinline__ void gemm_bb_body(const u16* __restrict__ A, const u16* __restrict__ B,
                                             CT* __restrict__ C, int bx, int by, bool tv,
                                             const float2* __restrict__ tab){
  __shared__ u16 As[128*64];
  __shared__ u16 Bs[128*64];
  const int tid = threadIdx.x, lane = tid & 63, w = tid >> 6;
  const int m0 = by*128, n0 = bx*128;
  const int wr = (w >> 1)*64, wc = (w & 1)*64;
  const int l15 = lane & 15, lg = lane >> 4;
  f32x4 acc[4][4];
#pragma unroll
  for (int i = 0; i < 4; i++)
#pragma unroll
    for (int j = 0; j < 4; j++) acc[i][j] = (f32x4){0.f,0.f,0.f,0.f};

  for (int kt = 0; kt < DMn; kt += 64){
    __syncthreads();
#pragma unroll
    for (int i = 0; i < 4; i++){
      const int c = i*256 + tid, row = c >> 3, cc = c & 7;
      gload16(A + (size_t)(m0 + row)*DMn + kt + ((cc ^ (row&7))<<3), &As[(size_t)c<<3]);
    }
#pragma unroll
    for (int i = 0; i < 4; i++){
      const int c = i*256 + tid, row = c >> 3, cc = c & 7;
      gload16(B + (size_t)(n0 + row)*DMn + kt + ((cc ^ (row&7))<<3), &Bs[(size_t)c<<3]);
    }
    __syncthreads();

#pragma unroll
    for (int kk = 0; kk < 2; kk++){
      bf16x8 af[4], bfr[4];
      const int ch = kk*4 + lg;
#pragma unroll
      for (int i = 0; i < 4; i++){
        const int row = wr + i*16 + l15;
        af[i] = *(const bf16x8*)&As[row*64 + ((ch ^ (row&7))<<3)];
      }
#pragma unroll
      for (int j = 0; j < 4; j++){
        const int col = wc + j*16 + l15;
        bfr[j] = *(const bf16x8*)&Bs[col*64 + ((ch ^ (col&7))<<3)];
      }
#pragma unroll
      for (int i = 0; i < 4; i++)
#pragma unroll
        for (int j = 0; j < 4; j++)
          acc[i][j] = __builtin_amdgcn_mfma_f32_16x16x32_bf16(af[i], bfr[j], acc[i][j], 0, 0, 0);
    }
  }

  if (tv){
#pragma unroll
    for (int i = 0; i < 4; i++)
#pragma unroll
      for (int j = 0; j < 4; j++){
        const int row = m0 + wr + i*16 + lg*4;
        const int col = n0 + wc + j*16 + l15;
        ushort4 o = { f2bf(acc[i][j][0]), f2bf(acc[i][j][1]), f2bf(acc[i][j][2]), f2bf(acc[i][j][3]) };
        *(ushort4*)((u16*)C + (size_t)(((row>>11)<<10) + col)*SEQn + (row & (SEQn-1))) = o;
      }
    return;
  }
  if constexpr (sizeof(CT) == 2){
    if (tab){        // fused RoPE epilogue (Q/K projections)
#pragma unroll
      for (int i = 0; i < 4; i++)
#pragma unroll
        for (int j = 0; j < 4; j++){
          const int col = n0 + wc + j*16 + l15;
          const int k = (col & 63) >> 1;
          const float sgn = (col & 1) ? 1.0f : -1.0f;
#pragma unroll
          for (int r = 0; r < 4; r++){
            const int row = m0 + wr + i*16 + lg*4 + r;
            const int s = row & (SEQn - 1);
            float x = acc[i][j][r];
            float p = __shfl_xor(x, 1);
            float2 cs = tab[(s << 5) | k];
            C[(size_t)row*DMn + col] = f2bf(fmaf(x, cs.x, sgn * p * cs.y));
          }
        }
      return;
    }
  }
#pragma unroll
  for (int i = 0; i < 4; i++)
#pragma unroll
    for (int j = 0; j < 4; j++)
#pragma unroll
      for (int r = 0; r < 4; r++){
        const int row = m0 + wr + i*16 + lg*4 + r;
        const int col = n0 + wc + j*16 + l15;
        if constexpr (sizeof(CT) == 2) C[(size_t)row*DMn + col] = f2bf(acc[i][j][r]);
        else                           C[(size_t)row*DMn + col] = acc[i][j][r];
      }
}

__global__ __launch_bounds__(256) void gemm_qkv_bb(const u16* A0, const u16* A1, const u16* A2,
                                                   const u16* W0, const u16* W1, const u16* W2,
                                                   u16* C0, u16* C1, u16* C2,
                                                   const float2* tab){
  const int z = blockIdx.z;
  const u16* A = (z == 0) ? A0 : (z == 1) ? A1 : A2;
  const u16* W = (z == 0) ? W0 : (z == 1) ? W1 : W2;
  u16*       C = (z == 0) ? C0 : (z == 1) ? C1 : C2;
  gemm_bb_body<u16>(A, W, C, blockIdx.x, blockIdx.y, z == 2, (z < 2) ? tab : nullptr);
}
__global__ __launch_bounds__(256) void gemm_out_bb(const u16* A, const u16* W, float* C){
  gemm_bb_body<float>(A, W, C, blockIdx.x, blockIdx.y, false, nullptr);
}

// ---------------- FALLBACK f32-input GEMM ----------------
template<typename AT, typename CT>
__device__ __forceinline__ void gemm_body(const AT* __restrict__ A, const float* __restrict__ W,
                                          CT* __restrict__ C, int bx, int by, bool tv){
  __shared__ u16 As[128*64];
  __shared__ u16 Bs[128*64];
  const int tid = threadIdx.x, lane = tid & 63, w = tid >> 6;
  const int m0 = by*128, n0 = bx*128;
  const int wr = (w >> 1)*64, wc = (w & 1)*64;
  const int l15 = lane & 15, lg = lane >> 4;
  f32x4 acc[4][4];
#pragma unroll
  for (int i = 0; i < 4; i++)
#pragma unroll
    for (int j = 0; j < 4; j++) acc[i][j] = (f32x4){0.f,0.f,0.f,0.f};

  for (int kt = 0; kt < DMn; kt += 64){
    float4 wv[8];
#pragma unroll
    for (int it = 0; it < 8; it++){
      const int f = it*256 + tid, row = f >> 4, c4 = f & 15;
      wv[it] = *(const float4*)(W + (size_t)(n0 + row)*DMn + kt + c4*4);
    }
    if constexpr (sizeof(AT) == 4){
      float4 av[8];
#pragma unroll
      for (int it = 0; it < 8; it++){
        const int f = it*256 + tid, row = f >> 4, c4 = f & 15;
        av[it] = *(const float4*)((const float*)A + (size_t)(m0 + row)*DMn + kt + c4*4);
      }
      __syncthreads();
#pragma unroll
      for (int it = 0; it < 8; it++){
        const int f = it*256 + tid, row = f >> 4, c4 = f & 15;
        ushort4 o = { f2bf(av[it].x), f2bf(av[it].y), f2bf(av[it].z), f2bf(av[it].w) };
        *(ushort4*)&As[row*64 + (((c4>>1) ^ (row&7))<<3) + ((c4&1)<<2)] = o;
      }
    } else {
      uint4 av4[4];
#pragma unroll
      for (int it = 0; it < 4; it++){
        const int f = it*256 + tid, row = f >> 3, ch = f & 7;
        av4[it] = *(const uint4*)((const u16*)A + (size_t)(m0 + row)*DMn + kt + ch*8);
      }
      __syncthreads();
#pragma unroll
      for (int it = 0; it < 4; it++){
        const int f = it*256 + tid, row = f >> 3, ch = f & 7;
        *(uint4*)&As[row*64 + ((ch ^ (row&7))<<3)] = av4[it];
      }
    }
#pragma unroll
    for (int it = 0; it < 8; it++){
      const int f = it*256 + tid, row = f >> 4, c4 = f & 15;
      ushort4 o = { f2bf(wv[it].x), f2bf(wv[it].y), f2bf(wv[it].z), f2bf(wv[it].w) };
      *(ushort4*)&Bs[row*64 + (((c4>>1) ^ (row&7))<<3) + ((c4&1)<<2)] = o;
    }
    __syncthreads();

#pragma unroll
    for (int kk = 0; kk < 2; kk++){
      bf16x8 af[4], bfr[4];
      const int ch = kk*4 + lg;
#pragma unroll
      for (int i = 0; i < 4; i++){
        const int row = wr + i*16 + l15;
        af[i] = *(const bf16x8*)&As[row*64 + ((ch ^ (row&7))<<3)];
      }
#pragma unroll
      for (int j = 0; j < 4; j++){
        const int col = wc + j*16 + l15;
        bfr[j] = *(const bf16x8*)&Bs[col*64 + ((ch ^ (col&7))<<3)];
      }
#pragma unroll
      for (int i = 0; i < 4; i++)
#pragma unroll
        for (int j = 0; j < 4; j++)
          acc[i][j] = __builtin_amdgcn_mfma_f32_16x16x32_bf16(af[i], bfr[j], acc[i][j], 0, 0, 0);
    }
    __syncthreads();
  }

  if (tv){
#pragma unroll
    for (int i = 0; i < 4; i++)
#pragma unroll
      for (int j = 0; j < 4; j++){
        const int row = m0 + wr + i*16 + lg*4;
        const int col = n0 + wc + j*16 + l15;
        ushort4 o = { f2bf(acc[i][j][0]), f2bf(acc[i][j][1]), f2bf(acc[i][j][2]), f2bf(acc[i][j][3]) };
        *(ushort4*)((u16*)C + (size_t)(((row>>11)<<10) + col)*SEQn + (row & (SEQn-1))) = o;
      }
  } else {
#pragma unroll
    for (int i = 0; i < 4; i++)
#pragma unroll
      for (int j = 0; j < 4; j++)
#pragma unroll
        for (int r = 0; r < 4; r++){
          const int row = m0 + wr + i*16 + lg*4 + r;
          const int col = n0 + wc + j*16 + l15;
          if constexpr (sizeof(CT) == 2) C[(size_t)row*DMn + col] = f2bf(acc[i][j][r]);
          else                           C[(size_t)row*DMn + col] = acc[i][j][r];
        }
  }
}

__global__ __launch_bounds__(256) void gemm_qkv(const float* A0, const float* A1, const float* A2,
                                                const float* W0, const float* W1, const float* W2,
                                                u16* C0, u16* C1, u16* C2){
  const int z = blockIdx.z;
  const float* A = (z == 0) ? A0 : (z == 1) ? A1 : A2;
  const float* W = (z == 0) ? W0 : (z == 1) ? W1 : W2;
  u16*         C = (z == 0) ? C0 : (z == 1) ? C1 : C2;
  gemm_body<float, u16>(A, W, C, blockIdx.x, blockIdx.y, z == 2);
}
__global__ __launch_bounds__(256) void gemm_out(const u16* A, const float* W, float* C){
  gemm_body<u16, float>(A, W, C, blockIdx.x, blockIdx.y, false);
}

// ---------------- MFMA causal flash attention (round-16, best measured) ----------------
__device__ __forceinline__ void stage_issue(const u16* __restrict__ xk, const u16* __restrict__ xvT,
                                            u16* __restrict__ Kb, u16* __restrict__ Vb,
                                            size_t bhbase, size_t vtbase, int kt, int tid){
#pragma unroll
  for (int i = 0; i < 2; i++){
    const int c = i*256 + tid, row = c >> 3, cc = c & 7;
    gload16(xk + bhbase + (size_t)(kt + row)*DMn + ((cc ^ (row&7))<<3), &Kb[(size_t)c<<3]);
  }
#pragma unroll
  for (int i = 0; i < 2; i++){
    const int c = i*256 + tid, d = c >> 3, cc = c & 7;
    gload16(xvT + vtbase + (size_t)d*SEQn + kt + ((cc ^ (d&7))<<3), &Vb[(size_t)c<<3]);
  }
}

__device__ __forceinline__ void attn_phase(const u16* __restrict__ xq, const u16* __restrict__ xk,
                                           const u16* __restrict__ xvT, u16* __restrict__ xo,
                                           u16* __restrict__ Kl0, u16* __restrict__ Kl1,
                                           u16* __restrict__ Vl0, u16* __restrict__ Vl1,
                                           u16* __restrict__ Plw, size_t bhbase, size_t vtbase,
                                           int qt, int tid){
  const int lane = tid & 63, w = tid >> 6;
  const int l15 = lane & 15, lg = lane >> 4;
  const int qw = qt*64 + w*16;

  const u16* qptr = xq + bhbase + (size_t)(qw + l15)*DMn + lg*8;
  const bf16x8 qf0 = *(const bf16x8*)(qptr);
  const bf16x8 qf1 = *(const bf16x8*)(qptr + 32);

  const u16x8 ou = {0x3F80,0x3F80,0x3F80,0x3F80,0x3F80,0x3F80,0x3F80,0x3F80};
  const bf16x8 onesf = __builtin_bit_cast(bf16x8, ou);

  float mrow[4], lrow[4];          // mrow in RAW score units, init 0
  f32x4 accO[4];
#pragma unroll
  for (int r = 0; r < 4; r++){ mrow[r] = 0.f; lrow[r] = 0.f; }
#pragma unroll
  for (int df = 0; df < 4; df++) accO[df] = (f32x4){0.f,0.f,0.f,0.f};

  stage_issue(xk, xvT, Kl0, Vl0, bhbase, vtbase, 0, tid);
  __syncthreads();

  for (int t = 0; t <= qt; t++){
    const int kt = t*64;
    u16* Kc = (t & 1) ? Kl1 : Kl0;
    u16* Vc = (t & 1) ? Vl1 : Vl0;
    if (t < qt)
      stage_issue(xk, xvT, (t & 1) ? Kl0 : Kl1, (t & 1) ? Vl0 : Vl1, bhbase, vtbase, kt + 64, tid);

    f32x4 sc[4];
    __builtin_amdgcn_s_setprio(1);
#pragma unroll
    for (int f = 0; f < 4; f++){
      const int n = 16*f + l15;
      bf16x8 kb0 = *(const bf16x8*)&Kc[n*64 + (( lg    ^ (n&7))<<3)];
      bf16x8 kb1 = *(const bf16x8*)&Kc[n*64 + (((lg+4) ^ (n&7))<<3)];
      f32x4 z = (f32x4){0.f,0.f,0.f,0.f};
      z = __builtin_amdgcn_mfma_f32_16x16x32_bf16(qf0, kb0, z, 0, 0, 0);
      z = __builtin_amdgcn_mfma_f32_16x16x32_bf16(qf1, kb1, z, 0, 0, 0);
      sc[f] = z;
    }
    __builtin_amdgcn_s_setprio(0);

    // ---- mask (diagonal tile only) + LANE-LOCAL row max (no shuffles) ----
    const bool needmask = (kt + 63 > qw);
    float mx[4];
#pragma unroll
    for (int r = 0; r < 4; r++){
      float v0 = sc[0][r], v1 = sc[1][r], v2 = sc[2][r], v3 = sc[3][r];
      if (needmask){
        const int qg = qw + lg*4 + r;
        if (kt +      l15 > qg) v0 = -3e38f;
        if (kt + 16 + l15 > qg) v1 = -3e38f;
        if (kt + 32 + l15 > qg) v2 = -3e38f;
        if (kt + 48 + l15 > qg) v3 = -3e38f;
        sc[0][r]=v0; sc[1][r]=v1; sc[2][r]=v2; sc[3][r]=v3;
      }
      mx[r] = fmaxf(fmaxf(v0,v1), fmaxf(v2,v3));
    }
    // ---- defer-max check: __all over lane-local maxes == global check ----
    const float dm = fmaxf(fmaxf(mx[0]-mrow[0], mx[1]-mrow[1]),
                           fmaxf(mx[2]-mrow[2], mx[3]-mrow[3]));
    if (!__all(dm <= DEFER_RAW)){
      // rare path: full row-max reduce + rescale
#pragma unroll
      for (int r = 0; r < 4; r++){
        float v = mx[r];
        v = fmaxf(v, __shfl_xor(v, 1));
        v = fmaxf(v, __shfl_xor(v, 2));
        v = fmaxf(v, __shfl_xor(v, 4));
        v = fmaxf(v, __shfl_xor(v, 8));
        const float mn = fmaxf(mrow[r], v);
        const float corr = exp2f((mrow[r] - mn)*SSCALE);
        mrow[r] = mn;
        lrow[r] *= corr;
        accO[0][r] *= corr; accO[1][r] *= corr; accO[2][r] *= corr; accO[3][r] *= corr;
      }
    }
    // ---- P = exp2(fma(S,S,-mS)) -> full-width Pl [16 q][64 k] ----
#pragma unroll
    for (int r = 0; r < 4; r++){
      const float ms = -mrow[r]*SSCALE;
      const float p0 = exp2f(fmaf(sc[0][r], SSCALE, ms));
      const float p1 = exp2f(fmaf(sc[1][r], SSCALE, ms));
      const float p2 = exp2f(fmaf(sc[2][r], SSCALE, ms));
      const float p3 = exp2f(fmaf(sc[3][r], SSCALE, ms));
      u32 pk01, pk23;
      asm("v_cvt_pk_bf16_f32 %0, %1, %2" : "=v"(pk01) : "v"(p0), "v"(p1));
      asm("v_cvt_pk_bf16_f32 %0, %1, %2" : "=v"(pk23) : "v"(p2), "v"(p3));
      const int q = lg*4 + r, qb = q*64, qx = q&7;
      const int k0 = l15, k1 = 16+l15, k2 = 32+l15, k3 = 48+l15;
      Plw[qb + (((k0>>3) ^ qx)<<3) + (k0&7)] = (u16)(pk01 & 0xffffu);
      Plw[qb + (((k1>>3) ^ qx)<<3) + (k1&7)] = (u16)(pk01 >> 16);
      Plw[qb + (((k2>>3) ^ qx)<<3) + (k2&7)] = (u16)(pk23 & 0xffffu);
      Plw[qb + (((k3>>3) ^ qx)<<3) + (k3&7)] = (u16)(pk23 >> 16);
    }
    // ---- O += P V; l += P·1 via ones-B MFMA ----
    f32x4 lsum = (f32x4){0.f,0.f,0.f,0.f};
    __builtin_amdgcn_s_setprio(1);
#pragma unroll
    for (int ks = 0; ks < 2; ks++){
      bf16x8 pa = *(const bf16x8*)&Plw[ l15*64 + (((4*ks + lg) ^ (l15&7))<<3) ];
      lsum = __builtin_amdgcn_mfma_f32_16x16x32_bf16(pa, onesf, lsum, 0, 0, 0);
#pragma unroll
      for (int df = 0; df < 4; df++){
        const int d = 16*df + l15;
        bf16x8 vb = *(const bf16x8*)&Vc[ d*64 + (((4*ks + lg) ^ (d&7))<<3) ];
        accO[df] = __builtin_amdgcn_mfma_f32_16x16x32_bf16(pa, vb, accO[df], 0, 0, 0);
      }
    }
    __builtin_amdgcn_s_setprio(0);
#pragma unroll
    for (int r = 0; r < 4; r++) lrow[r] += lsum[r];

    __syncthreads();
  }

#pragma unroll
  for (int r = 0; r < 4; r++){
    const float inv = 1.0f / lrow[r];
    const int qg = qw + lg*4 + r;
    u16* dst = xo + bhbase + (size_t)qg*DMn;
#pragma unroll
    for (int df = 0; df < 4; df++)
      dst[16*df + l15] = f2bf(accO[df][r] * inv);
  }
}

// 1024 blocks: orig = [slot:2][qtB:3][bh:5]. Co-resident quad shares bh
// (K/V stream L2-shared, XCD = bh%8) with qt quad {qtB,31-qtB,8+qtB,23-qtB}
// -> exactly 66 tiles per CU. LDS 40KB -> 4 blocks/CU.
__global__ __launch_bounds__(256) void attn_mfma(const u16* __restrict__ xq, const u16* __restrict__ xk,
                                                 const u16* __restrict__ xvT, u16* __restrict__ xo){
  __shared__ u16 Kl[2][64*64];
  __shared__ u16 Vl[2][64*64];
  __shared__ u16 Pl[4][16*64];
  const int tid = threadIdx.x;
  const int orig = blockIdx.x;
  const int bh  = orig & 31;
  const int qtB = (orig >> 5) & 7;
  const int s   = orig >> 8;
  const int qt  = (s == 0) ? qtB : (s == 1) ? 31 - qtB : (s == 2) ? 8 + qtB : 23 - qtB;
  const int b = bh >> 4, h = bh & 15;
  const size_t bhbase = (size_t)b*SEQn*DMn + (size_t)h*DKn;
  const size_t vtbase = ((size_t)b*1024 + (size_t)h*64)*SEQn;
  u16* Plw = &Pl[tid >> 6][0];

  attn_phase(xq, xk, xvT, xo, &Kl[0][0], &Kl[1][0], &Vl[0][0], &Vl[1][0], Plw, bhbase, vtbase, qt, tid);
}

extern "C" void kernel_launch(void* const* d_in, const int* in_sizes, int n_in,
                              void* d_out, int out_size, void* d_ws, size_t ws_size,
                              hipStream_t stream){
  (void)in_sizes; (void)n_in;
  const float* Q  = (const float*)d_in[0];
  const float* K  = (const float*)d_in[1];
  const float* V  = (const float*)d_in[2];
  const int*  pos = (const int*)  d_in[3];
  const float* wq = (const float*)d_in[4];
  const float* wk = (const float*)d_in[5];
  const float* wv = (const float*)d_in[6];
  const float* wo = (const float*)d_in[7];

  const size_t SZ  = (size_t)MR*DMn;         // 4,194,304 elements
  const size_t TB  = SZ*2;                   // 8 MB per bf16 tensor
  const size_t WSZ = (size_t)DMn*DMn;
  const size_t WB  = WSZ*2;                  // 2 MB per bf16 weight
  const size_t TABB = (size_t)SEQn*32*8;     // 512 KB cos/sin table

  if (ws_size >= 6*TB + 4*WB + TABB){
    // ---- fast path: fused prep + gload_lds GEMMs + fused-RoPE epilogue ----
    char* w = (char*)d_ws;
    u16* bQ  = (u16*)(w);                    // reused as xo after gemm_qkv_bb
    u16* bK  = (u16*)(w + TB);
    u16* bV  = (u16*)(w + 2*TB);
    u16* bwq = (u16*)(w + 3*TB);
    u16* bwk = (u16*)(w + 3*TB + WB);
    u16* bwv = (u16*)(w + 3*TB + 2*WB);
    u16* bwo = (u16*)(w + 3*TB + 3*WB);
    u16* xq  = (u16*)(w + 3*TB + 4*WB);
    u16* xk  = (u16*)(w + 4*TB + 4*WB);
    u16* xvT = (u16*)(w + 5*TB + 4*WB);      // [b][h][d][s]
    float2* tab = (float2*)(w + 6*TB + 4*WB);
    u16* xo  = bQ;

    dim3 pg((int)(SZ/4/256), 8);             // (4096, 8)
    prep_all<<<pg, 256, 0, stream>>>(Q, K, V, wq, wk, wv, wo,
                                     bQ, bK, bV, bwq, bwk, bwv, bwo, pos, tab);

    dim3 gg(DMn/128, MR/128, 3);
    gemm_qkv_bb<<<gg, 256, 0, stream>>>(bQ, bK, bV, bwq, bwk, bwv, xq, xk, xvT, tab);

    attn_mfma<<<1024, 256, 0, stream>>>(xq, xk, xvT, xo);

    dim3 go(DMn/128, MR/128);
    gemm_out_bb<<<go, 256, 0, stream>>>(xo, bwo, (float*)d_out);
  } else if (ws_size >= 4*TB){
    // ---- fallback: f32-input GEMMs + separate RoPE ----
    char* w = (char*)d_ws;
    u16* xq  = (u16*)(w);
    u16* xk  = (u16*)(w + TB);
    u16* xvT = (u16*)(w + 2*TB);
    u16* xo  = (u16*)(w + 3*TB);

    dim3 gg(DMn/128, MR/128, 3);
    gemm_qkv<<<gg, 256, 0, stream>>>(Q, K, V, wq, wk, wv, xq, xk, xvT);
    dim3 rg((int)(SZ/2/256), 2);
    rope2_kernel<<<rg, 256, 0, stream>>>((u32*)xq, (u32*)xk, pos);
    attn_mfma<<<1024, 256, 0, stream>>>(xq, xk, xvT, xo);
    dim3 go(DMn/128, MR/128);
    gemm_out<<<go, 256, 0, stream>>>(xo, wo, (float*)d_out);
  } else {
    hipMemsetAsync(d_out, 0x42, (size_t)out_size*4, stream);
  }
}

// Round 19
// 133.968 us; speedup vs baseline: 1.1383x; 1.0554x over previous
//
#include <hip/hip_runtime.h>

typedef unsigned short u16;
typedef unsigned int u32;
using bf16x8 = __attribute__((ext_vector_type(8))) __bf16;
using u16x8  = __attribute__((ext_vector_type(8))) u16;
using f32x4  = __attribute__((ext_vector_type(4))) float;

#define SEQn   2048
#define DMn    1024
#define NHn    16
#define DKn    64
#define BATCHn 2
#define MR     (BATCHn*SEQn)   // 4096 rows

#define SSCALE 0.18033688f     // 1/sqrt(64) * log2(e)
#define DEFER_RAW 63.77f       // 11.5 log2-units in raw-score units

__device__ __forceinline__ u16 f2bf(float f){
  u32 u = __builtin_bit_cast(u32, f);
  u32 r = (u + 0x7FFFu + ((u >> 16) & 1u)) >> 16;   // RNE
  return (u16)r;
}
__device__ __forceinline__ float bf2f(u32 b){ return __builtin_bit_cast(float, b << 16); }

// async global->LDS, 16B per lane (linear dest = wave base + lane*16)
__device__ __forceinline__ void gload16(const void* g, void* l){
  __builtin_amdgcn_global_load_lds((const __attribute__((address_space(1))) unsigned int*)g,
                                   (__attribute__((address_space(3))) unsigned int*)l, 16, 0, 0);
}

// ---------------- fused prep: f32->bf16 converts + RoPE table (one launch) ----------------
__global__ __launch_bounds__(256) void prep_all(const float* __restrict__ Q, const float* __restrict__ K,
                                                const float* __restrict__ V,
                                                const float* __restrict__ w0, const float* __restrict__ w1,
                                                const float* __restrict__ w2, const float* __restrict__ w3,
                                                u16* __restrict__ dQ, u16* __restrict__ dK, u16* __restrict__ dV,
                                                u16* __restrict__ dw0, u16* __restrict__ dw1,
                                                u16* __restrict__ dw2, u16* __restrict__ dw3,
                                                const int* __restrict__ pos, float2* __restrict__ tab){
  const int y = blockIdx.y;
  const int i = blockIdx.x*256 + threadIdx.x;
  if (y == 7){
    if (i >= SEQn*32) return;
    int s = i >> 5, k = i & 31;
    float inv = powf(10000.0f, -(float)k * (1.0f/32.0f));
    float a = (float)pos[s] * inv;
    float sn, cs;
    sincosf(a, &sn, &cs);
    tab[i] = make_float2(cs, sn);
    return;
  }
  const float* s; u16* d;
  if      (y == 0){ s = Q;  d = dQ;  }
  else if (y == 1){ s = K;  d = dK;  }
  else if (y == 2){ s = V;  d = dV;  }
  else {
    if (i >= (DMn*DMn)/4) return;
    s = (y == 3) ? w0 : (y == 4) ? w1 : (y == 5) ? w2 : w3;
    d = (y == 3) ? dw0 : (y == 4) ? dw1 : (y == 5) ? dw2 : dw3;
  }
  float4 v = ((const float4*)s)[i];
  ushort4 o = { f2bf(v.x), f2bf(v.y), f2bf(v.z), f2bf(v.w) };
  ((ushort4*)d)[i] = o;
}

// ---------------- RoPE in place (fallback path only) ----------------
__global__ __launch_bounds__(256) void rope2_kernel(u32* __restrict__ xq, u32* __restrict__ xk,
                                                    const int* __restrict__ pos){
  u32* x = blockIdx.y ? xk : xq;
  int p = blockIdx.x*256 + threadIdx.x;
  int s = (p >> 9) & (SEQn - 1);
  int k = p & 31;
  float inv = powf(10000.0f, -(float)k * (1.0f/32.0f));
  float a = (float)pos[s] * inv;
  float sn, cs;
  sincosf(a, &sn, &cs);
  u32 u = x[p];
  float xe = bf2f(u & 0xffffu);
  float xo = bf2f(u >> 16);
  float re = xe*cs - xo*sn;
  float ro = xe*sn + xo*cs;
  x[p] = (u32)f2bf(re) | ((u32)f2bf(ro) << 16);
}

// ---------------- bf16 MFMA GEMM, m97 structure: C = A * B^T (128x128 tile) ----------------
template<typename CT>
__device__ __forceinline__ void gemm_bb_body(const u16* __restrict__ A, const u16* __restrict__ B,
                                             CT* __restrict__ C, int bx, int by, bool tv,
                                             const float2* __restrict__ tab){
  __shared__ u16 As[128*64];
  __shared__ u16 Bs[128*64];
  const int tid = threadIdx.x, lane = tid & 63, w = tid >> 6;
  const int m0 = by*128, n0 = bx*128;
  const int wr = (w >> 1)*64, wc = (w & 1)*64;
  const int l15 = lane & 15, lg = lane >> 4;
  f32x4 acc[4][4];
#pragma unroll
  for (int i = 0; i < 4; i++)
#pragma unroll
    for (int j = 0; j < 4; j++) acc[i][j] = (f32x4){0.f,0.f,0.f,0.f};

  for (int kt = 0; kt < DMn; kt += 64){
    __syncthreads();
#pragma unroll
    for (int i = 0; i < 4; i++){
      const int c = i*256 + tid, row = c >> 3, cc = c & 7;
      gload16(A + (size_t)(m0 + row)*DMn + kt + ((cc ^ (row&7))<<3), &As[(size_t)c<<3]);
    }
#pragma unroll
    for (int i = 0; i < 4; i++){
      const int c = i*256 + tid, row = c >> 3, cc = c & 7;
      gload16(B + (size_t)(n0 + row)*DMn + kt + ((cc ^ (row&7))<<3), &Bs[(size_t)c<<3]);
    }
    __syncthreads();

#pragma unroll
    for (int kk = 0; kk < 2; kk++){
      bf16x8 af[4], bfr[4];
      const int ch = kk*4 + lg;
#pragma unroll
      for (int i = 0; i < 4; i++){
        const int row = wr + i*16 + l15;
        af[i] = *(const bf16x8*)&As[row*64 + ((ch ^ (row&7))<<3)];
      }
#pragma unroll
      for (int j = 0; j < 4; j++){
        const int col = wc + j*16 + l15;
        bfr[j] = *(const bf16x8*)&Bs[col*64 + ((ch ^ (col&7))<<3)];
      }
#pragma unroll
      for (int i = 0; i < 4; i++)
#pragma unroll
        for (int j = 0; j < 4; j++)
          acc[i][j] = __builtin_amdgcn_mfma_f32_16x16x32_bf16(af[i], bfr[j], acc[i][j], 0, 0, 0);
    }
  }

  if (tv){
#pragma unroll
    for (int i = 0; i < 4; i++)
#pragma unroll
      for (int j = 0; j < 4; j++){
        const int row = m0 + wr + i*16 + lg*4;
        const int col = n0 + wc + j*16 + l15;
        ushort4 o = { f2bf(acc[i][j][0]), f2bf(acc[i][j][1]), f2bf(acc[i][j][2]), f2bf(acc[i][j][3]) };
        *(ushort4*)((u16*)C + (size_t)(((row>>11)<<10) + col)*SEQn + (row & (SEQn-1))) = o;
      }
    return;
  }
  if constexpr (sizeof(CT) == 2){
    if (tab){        // fused RoPE epilogue (Q/K projections)
#pragma unroll
      for (int i = 0; i < 4; i++)
#pragma unroll
        for (int j = 0; j < 4; j++){
          const int col = n0 + wc + j*16 + l15;
          const int k = (col & 63) >> 1;
          const float sgn = (col & 1) ? 1.0f : -1.0f;
#pragma unroll
          for (int r = 0; r < 4; r++){
            const int row = m0 + wr + i*16 + lg*4 + r;
            const int s = row & (SEQn - 1);
            float x = acc[i][j][r];
            float p = __shfl_xor(x, 1);
            float2 cs = tab[(s << 5) | k];
            C[(size_t)row*DMn + col] = f2bf(fmaf(x, cs.x, sgn * p * cs.y));
          }
        }
      return;
    }
  }
#pragma unroll
  for (int i = 0; i < 4; i++)
#pragma unroll
    for (int j = 0; j < 4; j++)
#pragma unroll
      for (int r = 0; r < 4; r++){
        const int row = m0 + wr + i*16 + lg*4 + r;
        const int col = n0 + wc + j*16 + l15;
        if constexpr (sizeof(CT) == 2) C[(size_t)row*DMn + col] = f2bf(acc[i][j][r]);
        else                           C[(size_t)row*DMn + col] = acc[i][j][r];
      }
}

__global__ __launch_bounds__(256) void gemm_qkv_bb(const u16* A0, const u16* A1, const u16* A2,
                                                   const u16* W0, const u16* W1, const u16* W2,
                                                   u16* C0, u16* C1, u16* C2,
                                                   const float2* tab){
  const int z = blockIdx.z;
  const u16* A = (z == 0) ? A0 : (z == 1) ? A1 : A2;
  const u16* W = (z == 0) ? W0 : (z == 1) ? W1 : W2;
  u16*       C = (z == 0) ? C0 : (z == 1) ? C1 : C2;
  gemm_bb_body<u16>(A, W, C, blockIdx.x, blockIdx.y, z == 2, (z < 2) ? tab : nullptr);
}

// ---------------- output projection: 64x128 tile (512 blocks = 2/CU latency hiding) ----------------
// Same verified fragment mappings / K-loop order as gemm_bb_body; M-tile halved.
__global__ __launch_bounds__(256) void gemm_out_bb64(const u16* __restrict__ A, const u16* __restrict__ B,
                                                     float* __restrict__ C){
  __shared__ u16 As[64*64];
  __shared__ u16 Bs[128*64];
  const int tid = threadIdx.x, lane = tid & 63, w = tid >> 6;
  const int m0 = blockIdx.y*64, n0 = blockIdx.x*128;
  const int wr = (w >> 1)*32, wc = (w & 1)*64;
  const int l15 = lane & 15, lg = lane >> 4;
  f32x4 acc[2][4];
#pragma unroll
  for (int i = 0; i < 2; i++)
#pragma unroll
    for (int j = 0; j < 4; j++) acc[i][j] = (f32x4){0.f,0.f,0.f,0.f};

  for (int kt = 0; kt < DMn; kt += 64){
    __syncthreads();
#pragma unroll
    for (int i = 0; i < 2; i++){
      const int c = i*256 + tid, row = c >> 3, cc = c & 7;
      gload16(A + (size_t)(m0 + row)*DMn + kt + ((cc ^ (row&7))<<3), &As[(size_t)c<<3]);
    }
#pragma unroll
    for (int i = 0; i < 4; i++){
      const int c = i*256 + tid, row = c >> 3, cc = c & 7;
      gload16(B + (size_t)(n0 + row)*DMn + kt + ((cc ^ (row&7))<<3), &Bs[(size_t)c<<3]);
    }
    __syncthreads();

#pragma unroll
    for (int kk = 0; kk < 2; kk++){
      bf16x8 af[2], bfr[4];
      const int ch = kk*4 + lg;
#pragma unroll
      for (int i = 0; i < 2; i++){
        const int row = wr + i*16 + l15;
        af[i] = *(const bf16x8*)&As[row*64 + ((ch ^ (row&7))<<3)];
      }
#pragma unroll
      for (int j = 0; j < 4; j++){
        const int col = wc + j*16 + l15;
        bfr[j] = *(const bf16x8*)&Bs[col*64 + ((ch ^ (col&7))<<3)];
      }
#pragma unroll
      for (int i = 0; i < 2; i++)
#pragma unroll
        for (int j = 0; j < 4; j++)
          acc[i][j] = __builtin_amdgcn_mfma_f32_16x16x32_bf16(af[i], bfr[j], acc[i][j], 0, 0, 0);
    }
  }

#pragma unroll
  for (int i = 0; i < 2; i++)
#pragma unroll
    for (int j = 0; j < 4; j++)
#pragma unroll
      for (int r = 0; r < 4; r++){
        const int row = m0 + wr + i*16 + lg*4 + r;
        const int col = n0 + wc + j*16 + l15;
        C[(size_t)row*DMn + col] = acc[i][j][r];
      }
}

// ---------------- FALLBACK f32-input GEMM ----------------
template<typename AT, typename CT>
__device__ __forceinline__ void gemm_body(const AT* __restrict__ A, const float* __restrict__ W,
                                          CT* __restrict__ C, int bx, int by, bool tv){
  __shared__ u16 As[128*64];
  __shared__ u16 Bs[128*64];
  const int tid = threadIdx.x, lane = tid & 63, w = tid >> 6;
  const int m0 = by*128, n0 = bx*128;
  const int wr = (w >> 1)*64, wc = (w & 1)*64;
  const int l15 = lane & 15, lg = lane >> 4;
  f32x4 acc[4][4];
#pragma unroll
  for (int i = 0; i < 4; i++)
#pragma unroll
    for (int j = 0; j < 4; j++) acc[i][j] = (f32x4){0.f,0.f,0.f,0.f};

  for (int kt = 0; kt < DMn; kt += 64){
    float4 wv[8];
#pragma unroll
    for (int it = 0; it < 8; it++){
      const int f = it*256 + tid, row = f >> 4, c4 = f & 15;
      wv[it] = *(const float4*)(W + (size_t)(n0 + row)*DMn + kt + c4*4);
    }
    if constexpr (sizeof(AT) == 4){
      float4 av[8];
#pragma unroll
      for (int it = 0; it < 8; it++){
        const int f = it*256 + tid, row = f >> 4, c4 = f & 15;
        av[it] = *(const float4*)((const float*)A + (size_t)(m0 + row)*DMn + kt + c4*4);
      }
      __syncthreads();
#pragma unroll
      for (int it = 0; it < 8; it++){
        const int f = it*256 + tid, row = f >> 4, c4 = f & 15;
        ushort4 o = { f2bf(av[it].x), f2bf(av[it].y), f2bf(av[it].z), f2bf(av[it].w) };
        *(ushort4*)&As[row*64 + (((c4>>1) ^ (row&7))<<3) + ((c4&1)<<2)] = o;
      }
    } else {
      uint4 av4[4];
#pragma unroll
      for (int it = 0; it < 4; it++){
        const int f = it*256 + tid, row = f >> 3, ch = f & 7;
        av4[it] = *(const uint4*)((const u16*)A + (size_t)(m0 + row)*DMn + kt + ch*8);
      }
      __syncthreads();
#pragma unroll
      for (int it = 0; it < 4; it++){
        const int f = it*256 + tid, row = f >> 3, ch = f & 7;
        *(uint4*)&As[row*64 + ((ch ^ (row&7))<<3)] = av4[it];
      }
    }
#pragma unroll
    for (int it = 0; it < 8; it++){
      const int f = it*256 + tid, row = f >> 4, c4 = f & 15;
      ushort4 o = { f2bf(wv[it].x), f2bf(wv[it].y), f2bf(wv[it].z), f2bf(wv[it].w) };
      *(ushort4*)&Bs[row*64 + (((c4>>1) ^ (row&7))<<3) + ((c4&1)<<2)] = o;
    }
    __syncthreads();

#pragma unroll
    for (int kk = 0; kk < 2; kk++){
      bf16x8 af[4], bfr[4];
      const int ch = kk*4 + lg;
#pragma unroll
      for (int i = 0; i < 4; i++){
        const int row = wr + i*16 + l15;
        af[i] = *(const bf16x8*)&As[row*64 + ((ch ^ (row&7))<<3)];
      }
#pragma unroll
      for (int j = 0; j < 4; j++){
        const int col = wc + j*16 + l15;
        bfr[j] = *(const bf16x8*)&Bs[col*64 + ((ch ^ (col&7))<<3)];
      }
#pragma unroll
      for (int i = 0; i < 4; i++)
#pragma unroll
        for (int j = 0; j < 4; j++)
          acc[i][j] = __builtin_amdgcn_mfma_f32_16x16x32_bf16(af[i], bfr[j], acc[i][j], 0, 0, 0);
    }
    __syncthreads();
  }

  if (tv){
#pragma unroll
    for (int i = 0; i < 4; i++)
#pragma unroll
      for (int j = 0; j < 4; j++){
        const int row = m0 + wr + i*16 + lg*4;
        const int col = n0 + wc + j*16 + l15;
        ushort4 o = { f2bf(acc[i][j][0]), f2bf(acc[i][j][1]), f2bf(acc[i][j][2]), f2bf(acc[i][j][3]) };
        *(ushort4*)((u16*)C + (size_t)(((row>>11)<<10) + col)*SEQn + (row & (SEQn-1))) = o;
      }
  } else {
#pragma unroll
    for (int i = 0; i < 4; i++)
#pragma unroll
      for (int j = 0; j < 4; j++)
#pragma unroll
        for (int r = 0; r < 4; r++){
          const int row = m0 + wr + i*16 + lg*4 + r;
          const int col = n0 + wc + j*16 + l15;
          if constexpr (sizeof(CT) == 2) C[(size_t)row*DMn + col] = f2bf(acc[i][j][r]);
          else                           C[(size_t)row*DMn + col] = acc[i][j][r];
        }
  }
}

__global__ __launch_bounds__(256) void gemm_qkv(const float* A0, const float* A1, const float* A2,
                                                const float* W0, const float* W1, const float* W2,
                                                u16* C0, u16* C1, u16* C2){
  const int z = blockIdx.z;
  const float* A = (z == 0) ? A0 : (z == 1) ? A1 : A2;
  const float* W = (z == 0) ? W0 : (z == 1) ? W1 : W2;
  u16*         C = (z == 0) ? C0 : (z == 1) ? C1 : C2;
  gemm_body<float, u16>(A, W, C, blockIdx.x, blockIdx.y, z == 2);
}
__global__ __launch_bounds__(256) void gemm_out(const u16* A, const float* W, float* C){
  gemm_body<u16, float>(A, W, C, blockIdx.x, blockIdx.y, false);
}

// ---------------- MFMA causal flash attention (round-16, best measured) ----------------
__device__ __forceinline__ void stage_issue(const u16* __restrict__ xk, const u16* __restrict__ xvT,
                                            u16* __restrict__ Kb, u16* __restrict__ Vb,
                                            size_t bhbase, size_t vtbase, int kt, int tid){
#pragma unroll
  for (int i = 0; i < 2; i++){
    const int c = i*256 + tid, row = c >> 3, cc = c & 7;
    gload16(xk + bhbase + (size_t)(kt + row)*DMn + ((cc ^ (row&7))<<3), &Kb[(size_t)c<<3]);
  }
#pragma unroll
  for (int i = 0; i < 2; i++){
    const int c = i*256 + tid, d = c >> 3, cc = c & 7;
    gload16(xvT + vtbase + (size_t)d*SEQn + kt + ((cc ^ (d&7))<<3), &Vb[(size_t)c<<3]);
  }
}

__device__ __forceinline__ void attn_phase(const u16* __restrict__ xq, const u16* __restrict__ xk,
                                           const u16* __restrict__ xvT, u16* __restrict__ xo,
                                           u16* __restrict__ Kl0, u16* __restrict__ Kl1,
                                           u16* __restrict__ Vl0, u16* __restrict__ Vl1,
                                           u16* __restrict__ Plw, size_t bhbase, size_t vtbase,
                                           int qt, int tid){
  const int lane = tid & 63, w = tid >> 6;
  const int l15 = lane & 15, lg = lane >> 4;
  const int qw = qt*64 + w*16;

  const u16* qptr = xq + bhbase + (size_t)(qw + l15)*DMn + lg*8;
  const bf16x8 qf0 = *(const bf16x8*)(qptr);
  const bf16x8 qf1 = *(const bf16x8*)(qptr + 32);

  const u16x8 ou = {0x3F80,0x3F80,0x3F80,0x3F80,0x3F80,0x3F80,0x3F80,0x3F80};
  const bf16x8 onesf = __builtin_bit_cast(bf16x8, ou);

  float mrow[4], lrow[4];          // mrow in RAW score units, init 0
  f32x4 accO[4];
#pragma unroll
  for (int r = 0; r < 4; r++){ mrow[r] = 0.f; lrow[r] = 0.f; }
#pragma unroll
  for (int df = 0; df < 4; df++) accO[df] = (f32x4){0.f,0.f,0.f,0.f};

  stage_issue(xk, xvT, Kl0, Vl0, bhbase, vtbase, 0, tid);
  __syncthreads();

  for (int t = 0; t <= qt; t++){
    const int kt = t*64;
    u16* Kc = (t & 1) ? Kl1 : Kl0;
    u16* Vc = (t & 1) ? Vl1 : Vl0;
    if (t < qt)
      stage_issue(xk, xvT, (t & 1) ? Kl0 : Kl1, (t & 1) ? Vl0 : Vl1, bhbase, vtbase, kt + 64, tid);

    f32x4 sc[4];
    __builtin_amdgcn_s_setprio(1);
#pragma unroll
    for (int f = 0; f < 4; f++){
      const int n = 16*f + l15;
      bf16x8 kb0 = *(const bf16x8*)&Kc[n*64 + (( lg    ^ (n&7))<<3)];
      bf16x8 kb1 = *(const bf16x8*)&Kc[n*64 + (((lg+4) ^ (n&7))<<3)];
      f32x4 z = (f32x4){0.f,0.f,0.f,0.f};
      z = __builtin_amdgcn_mfma_f32_16x16x32_bf16(qf0, kb0, z, 0, 0, 0);
      z = __builtin_amdgcn_mfma_f32_16x16x32_bf16(qf1, kb1, z, 0, 0, 0);
      sc[f] = z;
    }
    __builtin_amdgcn_s_setprio(0);

    // ---- mask (diagonal tile only) + LANE-LOCAL row max (no shuffles) ----
    const bool needmask = (kt + 63 > qw);
    float mx[4];
#pragma unroll
    for (int r = 0; r < 4; r++){
      float v0 = sc[0][r], v1 = sc[1][r], v2 = sc[2][r], v3 = sc[3][r];
      if (needmask){
        const int qg = qw + lg*4 + r;
        if (kt +      l15 > qg) v0 = -3e38f;
        if (kt + 16 + l15 > qg) v1 = -3e38f;
        if (kt + 32 + l15 > qg) v2 = -3e38f;
        if (kt + 48 + l15 > qg) v3 = -3e38f;
        sc[0][r]=v0; sc[1][r]=v1; sc[2][r]=v2; sc[3][r]=v3;
      }
      mx[r] = fmaxf(fmaxf(v0,v1), fmaxf(v2,v3));
    }
    // ---- defer-max check: __all over lane-local maxes == global check ----
    const float dm = fmaxf(fmaxf(mx[0]-mrow[0], mx[1]-mrow[1]),
                           fmaxf(mx[2]-mrow[2], mx[3]-mrow[3]));
    if (!__all(dm <= DEFER_RAW)){
      // rare path: full row-max reduce + rescale
#pragma unroll
      for (int r = 0; r < 4; r++){
        float v = mx[r];
        v = fmaxf(v, __shfl_xor(v, 1));
        v = fmaxf(v, __shfl_xor(v, 2));
        v = fmaxf(v, __shfl_xor(v, 4));
        v = fmaxf(v, __shfl_xor(v, 8));
        const float mn = fmaxf(mrow[r], v);
        const float corr = exp2f((mrow[r] - mn)*SSCALE);
        mrow[r] = mn;
        lrow[r] *= corr;
        accO[0][r] *= corr; accO[1][r] *= corr; accO[2][r] *= corr; accO[3][r] *= corr;
      }
    }
    // ---- P = exp2(fma(S,S,-mS)) -> full-width Pl [16 q][64 k] ----
#pragma unroll
    for (int r = 0; r < 4; r++){
      const float ms = -mrow[r]*SSCALE;
      const float p0 = exp2f(fmaf(sc[0][r], SSCALE, ms));
      const float p1 = exp2f(fmaf(sc[1][r], SSCALE, ms));
      const float p2 = exp2f(fmaf(sc[2][r], SSCALE, ms));
      const float p3 = exp2f(fmaf(sc[3][r], SSCALE, ms));
      u32 pk01, pk23;
      asm("v_cvt_pk_bf16_f32 %0, %1, %2" : "=v"(pk01) : "v"(p0), "v"(p1));
      asm("v_cvt_pk_bf16_f32 %0, %1, %2" : "=v"(pk23) : "v"(p2), "v"(p3));
      const int q = lg*4 + r, qb = q*64, qx = q&7;
      const int k0 = l15, k1 = 16+l15, k2 = 32+l15, k3 = 48+l15;
      Plw[qb + (((k0>>3) ^ qx)<<3) + (k0&7)] = (u16)(pk01 & 0xffffu);
      Plw[qb + (((k1>>3) ^ qx)<<3) + (k1&7)] = (u16)(pk01 >> 16);
      Plw[qb + (((k2>>3) ^ qx)<<3) + (k2&7)] = (u16)(pk23 & 0xffffu);
      Plw[qb + (((k3>>3) ^ qx)<<3) + (k3&7)] = (u16)(pk23 >> 16);
    }
    // ---- O += P V; l += P·1 via ones-B MFMA ----
    f32x4 lsum = (f32x4){0.f,0.f,0.f,0.f};
    __builtin_amdgcn_s_setprio(1);
#pragma unroll
    for (int ks = 0; ks < 2; ks++){
      bf16x8 pa = *(const bf16x8*)&Plw[ l15*64 + (((4*ks + lg) ^ (l15&7))<<3) ];
      lsum = __builtin_amdgcn_mfma_f32_16x16x32_bf16(pa, onesf, lsum, 0, 0, 0);
#pragma unroll
      for (int df = 0; df < 4; df++){
        const int d = 16*df + l15;
        bf16x8 vb = *(const bf16x8*)&Vc[ d*64 + (((4*ks + lg) ^ (d&7))<<3) ];
        accO[df] = __builtin_amdgcn_mfma_f32_16x16x32_bf16(pa, vb, accO[df], 0, 0, 0);
      }
    }
    __builtin_amdgcn_s_setprio(0);
#pragma unroll
    for (int r = 0; r < 4; r++) lrow[r] += lsum[r];

    __syncthreads();
  }

#pragma unroll
  for (int r = 0; r < 4; r++){
    const float inv = 1.0f / lrow[r];
    const int qg = qw + lg*4 + r;
    u16* dst = xo + bhbase + (size_t)qg*DMn;
#pragma unroll
    for (int df = 0; df < 4; df++)
      dst[16*df + l15] = f2bf(accO[df][r] * inv);
  }
}

// 1024 blocks: orig = [slot:2][qtB:3][bh:5]. Co-resident quad shares bh
// (K/V stream L2-shared, XCD = bh%8) with qt quad {qtB,31-qtB,8+qtB,23-qtB}
// -> exactly 66 tiles per CU. LDS 40KB -> 4 blocks/CU.
__global__ __launch_bounds__(256) void attn_mfma(const u16* __restrict__ xq, const u16* __restrict__ xk,
                                                 const u16* __restrict__ xvT, u16* __restrict__ xo){
  __shared__ u16 Kl[2][64*64];
  __shared__ u16 Vl[2][64*64];
  __shared__ u16 Pl[4][16*64];
  const int tid = threadIdx.x;
  const int orig = blockIdx.x;
  const int bh  = orig & 31;
  const int qtB = (orig >> 5) & 7;
  const int s   = orig >> 8;
  const int qt  = (s == 0) ? qtB : (s == 1) ? 31 - qtB : (s == 2) ? 8 + qtB : 23 - qtB;
  const int b = bh >> 4, h = bh & 15;
  const size_t bhbase = (size_t)b*SEQn*DMn + (size_t)h*DKn;
  const size_t vtbase = ((size_t)b*1024 + (size_t)h*64)*SEQn;
  u16* Plw = &Pl[tid >> 6][0];

  attn_phase(xq, xk, xvT, xo, &Kl[0][0], &Kl[1][0], &Vl[0][0], &Vl[1][0], Plw, bhbase, vtbase, qt, tid);
}

extern "C" void kernel_launch(void* const* d_in, const int* in_sizes, int n_in,
                              void* d_out, int out_size, void* d_ws, size_t ws_size,
                              hipStream_t stream){
  (void)in_sizes; (void)n_in;
  const float* Q  = (const float*)d_in[0];
  const float* K  = (const float*)d_in[1];
  const float* V  = (const float*)d_in[2];
  const int*  pos = (const int*)  d_in[3];
  const float* wq = (const float*)d_in[4];
  const float* wk = (const float*)d_in[5];
  const float* wv = (const float*)d_in[6];
  const float* wo = (const float*)d_in[7];

  const size_t SZ  = (size_t)MR*DMn;         // 4,194,304 elements
  const size_t TB  = SZ*2;                   // 8 MB per bf16 tensor
  const size_t WSZ = (size_t)DMn*DMn;
  const size_t WB  = WSZ*2;                  // 2 MB per bf16 weight
  const size_t TABB = (size_t)SEQn*32*8;     // 512 KB cos/sin table

  if (ws_size >= 6*TB + 4*WB + TABB){
    // ---- fast path: fused prep + gload_lds GEMMs + fused-RoPE epilogue ----
    char* w = (char*)d_ws;
    u16* bQ  = (u16*)(w);                    // reused as xo after gemm_qkv_bb
    u16* bK  = (u16*)(w + TB);
    u16* bV  = (u16*)(w + 2*TB);
    u16* bwq = (u16*)(w + 3*TB);
    u16* bwk = (u16*)(w + 3*TB + WB);
    u16* bwv = (u16*)(w + 3*TB + 2*WB);
    u16* bwo = (u16*)(w + 3*TB + 3*WB);
    u16* xq  = (u16*)(w + 3*TB + 4*WB);
    u16* xk  = (u16*)(w + 4*TB + 4*WB);
    u16* xvT = (u16*)(w + 5*TB + 4*WB);      // [b][h][d][s]
    float2* tab = (float2*)(w + 6*TB + 4*WB);
    u16* xo  = bQ;

    dim3 pg((int)(SZ/4/256), 8);             // (4096, 8)
    prep_all<<<pg, 256, 0, stream>>>(Q, K, V, wq, wk, wv, wo,
                                     bQ, bK, bV, bwq, bwk, bwv, bwo, pos, tab);

    dim3 gg(DMn/128, MR/128, 3);
    gemm_qkv_bb<<<gg, 256, 0, stream>>>(bQ, bK, bV, bwq, bwk, bwv, xq, xk, xvT, tab);

    attn_mfma<<<1024, 256, 0, stream>>>(xq, xk, xvT, xo);

    dim3 go(DMn/128, MR/64);                 // (8, 64) = 512 blocks, 2/CU
    gemm_out_bb64<<<go, 256, 0, stream>>>(xo, bwo, (float*)d_out);
  } else if (ws_size >= 4*TB){
    // ---- fallback: f32-input GEMMs + separate RoPE ----
    char* w = (char*)d_ws;
    u16* xq  = (u16*)(w);
    u16* xk  = (u16*)(w + TB);
    u16* xvT = (u16*)(w + 2*TB);
    u16* xo  = (u16*)(w + 3*TB);

    dim3 gg(DMn/128, MR/128, 3);
    gemm_qkv<<<gg, 256, 0, stream>>>(Q, K, V, wq, wk, wv, xq, xk, xvT);
    dim3 rg((int)(SZ/2/256), 2);
    rope2_kernel<<<rg, 256, 0, stream>>>((u32*)xq, (u32*)xk, pos);
    attn_mfma<<<1024, 256, 0, stream>>>(xq, xk, xvT, xo);
    dim3 go(DMn/128, MR/128);
    gemm_out<<<go, 256, 0, stream>>>(xo, wo, (float*)d_out);
  } else {
    hipMemsetAsync(d_out, 0x42, (size_t)out_size*4, stream);
  }
}

// Round 20
// 127.458 us; speedup vs baseline: 1.1964x; 1.0511x over previous
//
#include <hip/hip_runtime.h>

typedef unsigned short u16;
typedef unsigned int u32;
using bf16x8 = __attribute__((ext_vector_type(8))) __bf16;
using u16x8  = __attribute__((ext_vector_type(8))) u16;
using f32x4  = __attribute__((ext_vector_type(4))) float;

#define SEQn   2048
#define DMn    1024
#define NHn    16
#define DKn    64
#define BATCHn 2
#define MR     (BATCHn*SEQn)   // 4096 rows

#define SSCALE 0.18033688f     // 1/sqrt(64) * log2(e)
#define DEFER_RAW 63.77f       // 11.5 log2-units in raw-score units

__device__ __forceinline__ u16 f2bf(float f){
  u32 u = __builtin_bit_cast(u32, f);
  u32 r = (u + 0x7FFFu + ((u >> 16) & 1u)) >> 16;   // RNE
  return (u16)r;
}
__device__ __forceinline__ float bf2f(u32 b){ return __builtin_bit_cast(float, b << 16); }

// async global->LDS, 16B per lane (linear dest = wave base + lane*16)
__device__ __forceinline__ void gload16(const void* g, void* l){
  __builtin_amdgcn_global_load_lds((const __attribute__((address_space(1))) unsigned int*)g,
                                   (__attribute__((address_space(3))) unsigned int*)l, 16, 0, 0);
}

// ---------------- fused prep: f32->bf16 converts + RoPE table (one launch) ----------------
__global__ __launch_bounds__(256) void prep_all(const float* __restrict__ Q, const float* __restrict__ K,
                                                const float* __restrict__ V,
                                                const float* __restrict__ w0, const float* __restrict__ w1,
                                                const float* __restrict__ w2, const float* __restrict__ w3,
                                                u16* __restrict__ dQ, u16* __restrict__ dK, u16* __restrict__ dV,
                                                u16* __restrict__ dw0, u16* __restrict__ dw1,
                                                u16* __restrict__ dw2, u16* __restrict__ dw3,
                                                const int* __restrict__ pos, float2* __restrict__ tab){
  const int y = blockIdx.y;
  const int i = blockIdx.x*256 + threadIdx.x;
  if (y == 7){
    if (i >= SEQn*32) return;
    int s = i >> 5, k = i & 31;
    float inv = powf(10000.0f, -(float)k * (1.0f/32.0f));
    float a = (float)pos[s] * inv;
    float sn, cs;
    sincosf(a, &sn, &cs);
    tab[i] = make_float2(cs, sn);
    return;
  }
  const float* s; u16* d;
  if      (y == 0){ s = Q;  d = dQ;  }
  else if (y == 1){ s = K;  d = dK;  }
  else if (y == 2){ s = V;  d = dV;  }
  else {
    if (i >= (DMn*DMn)/4) return;
    s = (y == 3) ? w0 : (y == 4) ? w1 : (y == 5) ? w2 : w3;
    d = (y == 3) ? dw0 : (y == 4) ? dw1 : (y == 5) ? dw2 : dw3;
  }
  float4 v = ((const float4*)s)[i];
  ushort4 o = { f2bf(v.x), f2bf(v.y), f2bf(v.z), f2bf(v.w) };
  ((ushort4*)d)[i] = o;
}

// ---------------- RoPE in place (fallback path only) ----------------
__global__ __launch_bounds__(256) void rope2_kernel(u32* __restrict__ xq, u32* __restrict__ xk,
                                                    const int* __restrict__ pos){
  u32* x = blockIdx.y ? xk : xq;
  int p = blockIdx.x*256 + threadIdx.x;
  int s = (p >> 9) & (SEQn - 1);
  int k = p & 31;
  float inv = powf(10000.0f, -(float)k * (1.0f/32.0f));
  float a = (float)pos[s] * inv;
  float sn, cs;
  sincosf(a, &sn, &cs);
  u32 u = x[p];
  float xe = bf2f(u & 0xffffu);
  float xo = bf2f(u >> 16);
  float re = xe*cs - xo*sn;
  float ro = xe*sn + xo*cs;
  x[p] = (u32)f2bf(re) | ((u32)f2bf(ro) << 16);
}

// ---------------- Q/K/V projection GEMM: 64x128 tile (1536 blocks = 6/CU) ----------------
// C = A * W^T with fused epilogues: tab -> RoPE (Q/K), tv -> transposed write (V).
// Same verified fragment mappings / per-element K-loop order as the 128x128 body.
__global__ __launch_bounds__(256) void gemm_qkv_bb64(const u16* A0, const u16* A1, const u16* A2,
                                                     const u16* W0, const u16* W1, const u16* W2,
                                                     u16* C0, u16* C1, u16* C2,
                                                     const float2* __restrict__ tab){
  __shared__ u16 As[64*64];
  __shared__ u16 Bs[128*64];
  const int z = blockIdx.z;
  const u16* A = (z == 0) ? A0 : (z == 1) ? A1 : A2;
  const u16* B = (z == 0) ? W0 : (z == 1) ? W1 : W2;
  u16*       C = (z == 0) ? C0 : (z == 1) ? C1 : C2;
  const bool tv = (z == 2);

  const int tid = threadIdx.x, lane = tid & 63, w = tid >> 6;
  const int m0 = blockIdx.y*64, n0 = blockIdx.x*128;
  const int wr = (w >> 1)*32, wc = (w & 1)*64;
  const int l15 = lane & 15, lg = lane >> 4;
  f32x4 acc[2][4];
#pragma unroll
  for (int i = 0; i < 2; i++)
#pragma unroll
    for (int j = 0; j < 4; j++) acc[i][j] = (f32x4){0.f,0.f,0.f,0.f};

  for (int kt = 0; kt < DMn; kt += 64){
    __syncthreads();
#pragma unroll
    for (int i = 0; i < 2; i++){
      const int c = i*256 + tid, row = c >> 3, cc = c & 7;
      gload16(A + (size_t)(m0 + row)*DMn + kt + ((cc ^ (row&7))<<3), &As[(size_t)c<<3]);
    }
#pragma unroll
    for (int i = 0; i < 4; i++){
      const int c = i*256 + tid, row = c >> 3, cc = c & 7;
      gload16(B + (size_t)(n0 + row)*DMn + kt + ((cc ^ (row&7))<<3), &Bs[(size_t)c<<3]);
    }
    __syncthreads();

#pragma unroll
    for (int kk = 0; kk < 2; kk++){
      bf16x8 af[2], bfr[4];
      const int ch = kk*4 + lg;
#pragma unroll
      for (int i = 0; i < 2; i++){
        const int row = wr + i*16 + l15;
        af[i] = *(const bf16x8*)&As[row*64 + ((ch ^ (row&7))<<3)];
      }
#pragma unroll
      for (int j = 0; j < 4; j++){
        const int col = wc + j*16 + l15;
        bfr[j] = *(const bf16x8*)&Bs[col*64 + ((ch ^ (col&7))<<3)];
      }
#pragma unroll
      for (int i = 0; i < 2; i++)
#pragma unroll
        for (int j = 0; j < 4; j++)
          acc[i][j] = __builtin_amdgcn_mfma_f32_16x16x32_bf16(af[i], bfr[j], acc[i][j], 0, 0, 0);
    }
  }

  if (tv){
#pragma unroll
    for (int i = 0; i < 2; i++)
#pragma unroll
      for (int j = 0; j < 4; j++){
        const int row = m0 + wr + i*16 + lg*4;
        const int col = n0 + wc + j*16 + l15;
        ushort4 o = { f2bf(acc[i][j][0]), f2bf(acc[i][j][1]), f2bf(acc[i][j][2]), f2bf(acc[i][j][3]) };
        *(ushort4*)(C + (size_t)(((row>>11)<<10) + col)*SEQn + (row & (SEQn-1))) = o;
      }
  } else {
#pragma unroll
    for (int i = 0; i < 2; i++)
#pragma unroll
      for (int j = 0; j < 4; j++){
        const int col = n0 + wc + j*16 + l15;
        const int k = (col & 63) >> 1;
        const float sgn = (col & 1) ? 1.0f : -1.0f;
#pragma unroll
        for (int r = 0; r < 4; r++){
          const int row = m0 + wr + i*16 + lg*4 + r;
          const int s = row & (SEQn - 1);
          float x = acc[i][j][r];
          float p = __shfl_xor(x, 1);
          float2 cs = tab[(s << 5) | k];
          C[(size_t)row*DMn + col] = f2bf(fmaf(x, cs.x, sgn * p * cs.y));
        }
      }
  }
}

// ---------------- output projection: 64x128 tile (512 blocks = 2/CU), round-19 validated ----------------
__global__ __launch_bounds__(256) void gemm_out_bb64(const u16* __restrict__ A, const u16* __restrict__ B,
                                                     float* __restrict__ C){
  __shared__ u16 As[64*64];
  __shared__ u16 Bs[128*64];
  const int tid = threadIdx.x, lane = tid & 63, w = tid >> 6;
  const int m0 = blockIdx.y*64, n0 = blockIdx.x*128;
  const int wr = (w >> 1)*32, wc = (w & 1)*64;
  const int l15 = lane & 15, lg = lane >> 4;
  f32x4 acc[2][4];
#pragma unroll
  for (int i = 0; i < 2; i++)
#pragma unroll
    for (int j = 0; j < 4; j++) acc[i][j] = (f32x4){0.f,0.f,0.f,0.f};

  for (int kt = 0; kt < DMn; kt += 64){
    __syncthreads();
#pragma unroll
    for (int i = 0; i < 2; i++){
      const int c = i*256 + tid, row = c >> 3, cc = c & 7;
      gload16(A + (size_t)(m0 + row)*DMn + kt + ((cc ^ (row&7))<<3), &As[(size_t)c<<3]);
    }
#pragma unroll
    for (int i = 0; i < 4; i++){
      const int c = i*256 + tid, row = c >> 3, cc = c & 7;
      gload16(B + (size_t)(n0 + row)*DMn + kt + ((cc ^ (row&7))<<3), &Bs[(size_t)c<<3]);
    }
    __syncthreads();

#pragma unroll
    for (int kk = 0; kk < 2; kk++){
      bf16x8 af[2], bfr[4];
      const int ch = kk*4 + lg;
#pragma unroll
      for (int i = 0; i < 2; i++){
        const int row = wr + i*16 + l15;
        af[i] = *(const bf16x8*)&As[row*64 + ((ch ^ (row&7))<<3)];
      }
#pragma unroll
      for (int j = 0; j < 4; j++){
        const int col = wc + j*16 + l15;
        bfr[j] = *(const bf16x8*)&Bs[col*64 + ((ch ^ (col&7))<<3)];
      }
#pragma unroll
      for (int i = 0; i < 2; i++)
#pragma unroll
        for (int j = 0; j < 4; j++)
          acc[i][j] = __builtin_amdgcn_mfma_f32_16x16x32_bf16(af[i], bfr[j], acc[i][j], 0, 0, 0);
    }
  }

#pragma unroll
  for (int i = 0; i < 2; i++)
#pragma unroll
    for (int j = 0; j < 4; j++)
#pragma unroll
      for (int r = 0; r < 4; r++){
        const int row = m0 + wr + i*16 + lg*4 + r;
        const int col = n0 + wc + j*16 + l15;
        C[(size_t)row*DMn + col] = acc[i][j][r];
      }
}

// ---------------- FALLBACK f32-input GEMM ----------------
template<typename AT, typename CT>
__device__ __forceinline__ void gemm_body(const AT* __restrict__ A, const float* __restrict__ W,
                                          CT* __restrict__ C, int bx, int by, bool tv){
  __shared__ u16 As[128*64];
  __shared__ u16 Bs[128*64];
  const int tid = threadIdx.x, lane = tid & 63, w = tid >> 6;
  const int m0 = by*128, n0 = bx*128;
  const int wr = (w >> 1)*64, wc = (w & 1)*64;
  const int l15 = lane & 15, lg = lane >> 4;
  f32x4 acc[4][4];
#pragma unroll
  for (int i = 0; i < 4; i++)
#pragma unroll
    for (int j = 0; j < 4; j++) acc[i][j] = (f32x4){0.f,0.f,0.f,0.f};

  for (int kt = 0; kt < DMn; kt += 64){
    float4 wv[8];
#pragma unroll
    for (int it = 0; it < 8; it++){
      const int f = it*256 + tid, row = f >> 4, c4 = f & 15;
      wv[it] = *(const float4*)(W + (size_t)(n0 + row)*DMn + kt + c4*4);
    }
    if constexpr (sizeof(AT) == 4){
      float4 av[8];
#pragma unroll
      for (int it = 0; it < 8; it++){
        const int f = it*256 + tid, row = f >> 4, c4 = f & 15;
        av[it] = *(const float4*)((const float*)A + (size_t)(m0 + row)*DMn + kt + c4*4);
      }
      __syncthreads();
#pragma unroll
      for (int it = 0; it < 8; it++){
        const int f = it*256 + tid, row = f >> 4, c4 = f & 15;
        ushort4 o = { f2bf(av[it].x), f2bf(av[it].y), f2bf(av[it].z), f2bf(av[it].w) };
        *(ushort4*)&As[row*64 + (((c4>>1) ^ (row&7))<<3) + ((c4&1)<<2)] = o;
      }
    } else {
      uint4 av4[4];
#pragma unroll
      for (int it = 0; it < 4; it++){
        const int f = it*256 + tid, row = f >> 3, ch = f & 7;
        av4[it] = *(const uint4*)((const u16*)A + (size_t)(m0 + row)*DMn + kt + ch*8);
      }
      __syncthreads();
#pragma unroll
      for (int it = 0; it < 4; it++){
        const int f = it*256 + tid, row = f >> 3, ch = f & 7;
        *(uint4*)&As[row*64 + ((ch ^ (row&7))<<3)] = av4[it];
      }
    }
#pragma unroll
    for (int it = 0; it < 8; it++){
      const int f = it*256 + tid, row = f >> 4, c4 = f & 15;
      ushort4 o = { f2bf(wv[it].x), f2bf(wv[it].y), f2bf(wv[it].z), f2bf(wv[it].w) };
      *(ushort4*)&Bs[row*64 + (((c4>>1) ^ (row&7))<<3) + ((c4&1)<<2)] = o;
    }
    __syncthreads();

#pragma unroll
    for (int kk = 0; kk < 2; kk++){
      bf16x8 af[4], bfr[4];
      const int ch = kk*4 + lg;
#pragma unroll
      for (int i = 0; i < 4; i++){
        const int row = wr + i*16 + l15;
        af[i] = *(const bf16x8*)&As[row*64 + ((ch ^ (row&7))<<3)];
      }
#pragma unroll
      for (int j = 0; j < 4; j++){
        const int col = wc + j*16 + l15;
        bfr[j] = *(const bf16x8*)&Bs[col*64 + ((ch ^ (col&7))<<3)];
      }
#pragma unroll
      for (int i = 0; i < 4; i++)
#pragma unroll
        for (int j = 0; j < 4; j++)
          acc[i][j] = __builtin_amdgcn_mfma_f32_16x16x32_bf16(af[i], bfr[j], acc[i][j], 0, 0, 0);
    }
    __syncthreads();
  }

  if (tv){
#pragma unroll
    for (int i = 0; i < 4; i++)
#pragma unroll
      for (int j = 0; j < 4; j++){
        const int row = m0 + wr + i*16 + lg*4;
        const int col = n0 + wc + j*16 + l15;
        ushort4 o = { f2bf(acc[i][j][0]), f2bf(acc[i][j][1]), f2bf(acc[i][j][2]), f2bf(acc[i][j][3]) };
        *(ushort4*)((u16*)C + (size_t)(((row>>11)<<10) + col)*SEQn + (row & (SEQn-1))) = o;
      }
  } else {
#pragma unroll
    for (int i = 0; i < 4; i++)
#pragma unroll
      for (int j = 0; j < 4; j++)
#pragma unroll
        for (int r = 0; r < 4; r++){
          const int row = m0 + wr + i*16 + lg*4 + r;
          const int col = n0 + wc + j*16 + l15;
          if constexpr (sizeof(CT) == 2) C[(size_t)row*DMn + col] = f2bf(acc[i][j][r]);
          else                           C[(size_t)row*DMn + col] = acc[i][j][r];
        }
  }
}

__global__ __launch_bounds__(256) void gemm_qkv(const float* A0, const float* A1, const float* A2,
                                                const float* W0, const float* W1, const float* W2,
                                                u16* C0, u16* C1, u16* C2){
  const int z = blockIdx.z;
  const float* A = (z == 0) ? A0 : (z == 1) ? A1 : A2;
  const float* W = (z == 0) ? W0 : (z == 1) ? W1 : W2;
  u16*         C = (z == 0) ? C0 : (z == 1) ? C1 : C2;
  gemm_body<float, u16>(A, W, C, blockIdx.x, blockIdx.y, z == 2);
}
__global__ __launch_bounds__(256) void gemm_out(const u16* A, const float* W, float* C){
  gemm_body<u16, float>(A, W, C, blockIdx.x, blockIdx.y, false);
}

// ---------------- MFMA causal flash attention (round-16, best measured) ----------------
__device__ __forceinline__ void stage_issue(const u16* __restrict__ xk, const u16* __restrict__ xvT,
                                            u16* __restrict__ Kb, u16* __restrict__ Vb,
                                            size_t bhbase, size_t vtbase, int kt, int tid){
#pragma unroll
  for (int i = 0; i < 2; i++){
    const int c = i*256 + tid, row = c >> 3, cc = c & 7;
    gload16(xk + bhbase + (size_t)(kt + row)*DMn + ((cc ^ (row&7))<<3), &Kb[(size_t)c<<3]);
  }
#pragma unroll
  for (int i = 0; i < 2; i++){
    const int c = i*256 + tid, d = c >> 3, cc = c & 7;
    gload16(xvT + vtbase + (size_t)d*SEQn + kt + ((cc ^ (d&7))<<3), &Vb[(size_t)c<<3]);
  }
}

__device__ __forceinline__ void attn_phase(const u16* __restrict__ xq, const u16* __restrict__ xk,
                                           const u16* __restrict__ xvT, u16* __restrict__ xo,
                                           u16* __restrict__ Kl0, u16* __restrict__ Kl1,
                                           u16* __restrict__ Vl0, u16* __restrict__ Vl1,
                                           u16* __restrict__ Plw, size_t bhbase, size_t vtbase,
                                           int qt, int tid){
  const int lane = tid & 63, w = tid >> 6;
  const int l15 = lane & 15, lg = lane >> 4;
  const int qw = qt*64 + w*16;

  const u16* qptr = xq + bhbase + (size_t)(qw + l15)*DMn + lg*8;
  const bf16x8 qf0 = *(const bf16x8*)(qptr);
  const bf16x8 qf1 = *(const bf16x8*)(qptr + 32);

  const u16x8 ou = {0x3F80,0x3F80,0x3F80,0x3F80,0x3F80,0x3F80,0x3F80,0x3F80};
  const bf16x8 onesf = __builtin_bit_cast(bf16x8, ou);

  float mrow[4], lrow[4];          // mrow in RAW score units, init 0
  f32x4 accO[4];
#pragma unroll
  for (int r = 0; r < 4; r++){ mrow[r] = 0.f; lrow[r] = 0.f; }
#pragma unroll
  for (int df = 0; df < 4; df++) accO[df] = (f32x4){0.f,0.f,0.f,0.f};

  stage_issue(xk, xvT, Kl0, Vl0, bhbase, vtbase, 0, tid);
  __syncthreads();

  for (int t = 0; t <= qt; t++){
    const int kt = t*64;
    u16* Kc = (t & 1) ? Kl1 : Kl0;
    u16* Vc = (t & 1) ? Vl1 : Vl0;
    if (t < qt)
      stage_issue(xk, xvT, (t & 1) ? Kl0 : Kl1, (t & 1) ? Vl0 : Vl1, bhbase, vtbase, kt + 64, tid);

    f32x4 sc[4];
    __builtin_amdgcn_s_setprio(1);
#pragma unroll
    for (int f = 0; f < 4; f++){
      const int n = 16*f + l15;
      bf16x8 kb0 = *(const bf16x8*)&Kc[n*64 + (( lg    ^ (n&7))<<3)];
      bf16x8 kb1 = *(const bf16x8*)&Kc[n*64 + (((lg+4) ^ (n&7))<<3)];
      f32x4 z = (f32x4){0.f,0.f,0.f,0.f};
      z = __builtin_amdgcn_mfma_f32_16x16x32_bf16(qf0, kb0, z, 0, 0, 0);
      z = __builtin_amdgcn_mfma_f32_16x16x32_bf16(qf1, kb1, z, 0, 0, 0);
      sc[f] = z;
    }
    __builtin_amdgcn_s_setprio(0);

    // ---- mask (diagonal tile only) + LANE-LOCAL row max (no shuffles) ----
    const bool needmask = (kt + 63 > qw);
    float mx[4];
#pragma unroll
    for (int r = 0; r < 4; r++){
      float v0 = sc[0][r], v1 = sc[1][r], v2 = sc[2][r], v3 = sc[3][r];
      if (needmask){
        const int qg = qw + lg*4 + r;
        if (kt +      l15 > qg) v0 = -3e38f;
        if (kt + 16 + l15 > qg) v1 = -3e38f;
        if (kt + 32 + l15 > qg) v2 = -3e38f;
        if (kt + 48 + l15 > qg) v3 = -3e38f;
        sc[0][r]=v0; sc[1][r]=v1; sc[2][r]=v2; sc[3][r]=v3;
      }
      mx[r] = fmaxf(fmaxf(v0,v1), fmaxf(v2,v3));
    }
    // ---- defer-max check: __all over lane-local maxes == global check ----
    const float dm = fmaxf(fmaxf(mx[0]-mrow[0], mx[1]-mrow[1]),
                           fmaxf(mx[2]-mrow[2], mx[3]-mrow[3]));
    if (!__all(dm <= DEFER_RAW)){
      // rare path: full row-max reduce + rescale
#pragma unroll
      for (int r = 0; r < 4; r++){
        float v = mx[r];
        v = fmaxf(v, __shfl_xor(v, 1));
        v = fmaxf(v, __shfl_xor(v, 2));
        v = fmaxf(v, __shfl_xor(v, 4));
        v = fmaxf(v, __shfl_xor(v, 8));
        const float mn = fmaxf(mrow[r], v);
        const float corr = exp2f((mrow[r] - mn)*SSCALE);
        mrow[r] = mn;
        lrow[r] *= corr;
        accO[0][r] *= corr; accO[1][r] *= corr; accO[2][r] *= corr; accO[3][r] *= corr;
      }
    }
    // ---- P = exp2(fma(S,S,-mS)) -> full-width Pl [16 q][64 k] ----
#pragma unroll
    for (int r = 0; r < 4; r++){
      const float ms = -mrow[r]*SSCALE;
      const float p0 = exp2f(fmaf(sc[0][r], SSCALE, ms));
      const float p1 = exp2f(fmaf(sc[1][r], SSCALE, ms));
      const float p2 = exp2f(fmaf(sc[2][r], SSCALE, ms));
      const float p3 = exp2f(fmaf(sc[3][r], SSCALE, ms));
      u32 pk01, pk23;
      asm("v_cvt_pk_bf16_f32 %0, %1, %2" : "=v"(pk01) : "v"(p0), "v"(p1));
      asm("v_cvt_pk_bf16_f32 %0, %1, %2" : "=v"(pk23) : "v"(p2), "v"(p3));
      const int q = lg*4 + r, qb = q*64, qx = q&7;
      const int k0 = l15, k1 = 16+l15, k2 = 32+l15, k3 = 48+l15;
      Plw[qb + (((k0>>3) ^ qx)<<3) + (k0&7)] = (u16)(pk01 & 0xffffu);
      Plw[qb + (((k1>>3) ^ qx)<<3) + (k1&7)] = (u16)(pk01 >> 16);
      Plw[qb + (((k2>>3) ^ qx)<<3) + (k2&7)] = (u16)(pk23 & 0xffffu);
      Plw[qb + (((k3>>3) ^ qx)<<3) + (k3&7)] = (u16)(pk23 >> 16);
    }
    // ---- O += P V; l += P·1 via ones-B MFMA ----
    f32x4 lsum = (f32x4){0.f,0.f,0.f,0.f};
    __builtin_amdgcn_s_setprio(1);
#pragma unroll
    for (int ks = 0; ks < 2; ks++){
      bf16x8 pa = *(const bf16x8*)&Plw[ l15*64 + (((4*ks + lg) ^ (l15&7))<<3) ];
      lsum = __builtin_amdgcn_mfma_f32_16x16x32_bf16(pa, onesf, lsum, 0, 0, 0);
#pragma unroll
      for (int df = 0; df < 4; df++){
        const int d = 16*df + l15;
        bf16x8 vb = *(const bf16x8*)&Vc[ d*64 + (((4*ks + lg) ^ (d&7))<<3) ];
        accO[df] = __builtin_amdgcn_mfma_f32_16x16x32_bf16(pa, vb, accO[df], 0, 0, 0);
      }
    }
    __builtin_amdgcn_s_setprio(0);
#pragma unroll
    for (int r = 0; r < 4; r++) lrow[r] += lsum[r];

    __syncthreads();
  }

#pragma unroll
  for (int r = 0; r < 4; r++){
    const float inv = 1.0f / lrow[r];
    const int qg = qw + lg*4 + r;
    u16* dst = xo + bhbase + (size_t)qg*DMn;
#pragma unroll
    for (int df = 0; df < 4; df++)
      dst[16*df + l15] = f2bf(accO[df][r] * inv);
  }
}

// 1024 blocks: orig = [slot:2][qtB:3][bh:5]. Co-resident quad shares bh
// (K/V stream L2-shared, XCD = bh%8) with qt quad {qtB,31-qtB,8+qtB,23-qtB}
// -> exactly 66 tiles per CU. LDS 40KB -> 4 blocks/CU.
__global__ __launch_bounds__(256) void attn_mfma(const u16* __restrict__ xq, const u16* __restrict__ xk,
                                                 const u16* __restrict__ xvT, u16* __restrict__ xo){
  __shared__ u16 Kl[2][64*64];
  __shared__ u16 Vl[2][64*64];
  __shared__ u16 Pl[4][16*64];
  const int tid = threadIdx.x;
  const int orig = blockIdx.x;
  const int bh  = orig & 31;
  const int qtB = (orig >> 5) & 7;
  const int s   = orig >> 8;
  const int qt  = (s == 0) ? qtB : (s == 1) ? 31 - qtB : (s == 2) ? 8 + qtB : 23 - qtB;
  const int b = bh >> 4, h = bh & 15;
  const size_t bhbase = (size_t)b*SEQn*DMn + (size_t)h*DKn;
  const size_t vtbase = ((size_t)b*1024 + (size_t)h*64)*SEQn;
  u16* Plw = &Pl[tid >> 6][0];

  attn_phase(xq, xk, xvT, xo, &Kl[0][0], &Kl[1][0], &Vl[0][0], &Vl[1][0], Plw, bhbase, vtbase, qt, tid);
}

extern "C" void kernel_launch(void* const* d_in, const int* in_sizes, int n_in,
                              void* d_out, int out_size, void* d_ws, size_t ws_size,
                              hipStream_t stream){
  (void)in_sizes; (void)n_in;
  const float* Q  = (const float*)d_in[0];
  const float* K  = (const float*)d_in[1];
  const float* V  = (const float*)d_in[2];
  const int*  pos = (const int*)  d_in[3];
  const float* wq = (const float*)d_in[4];
  const float* wk = (const float*)d_in[5];
  const float* wv = (const float*)d_in[6];
  const float* wo = (const float*)d_in[7];

  const size_t SZ  = (size_t)MR*DMn;         // 4,194,304 elements
  const size_t TB  = SZ*2;                   // 8 MB per bf16 tensor
  const size_t WSZ = (size_t)DMn*DMn;
  const size_t WB  = WSZ*2;                  // 2 MB per bf16 weight
  const size_t TABB = (size_t)SEQn*32*8;     // 512 KB cos/sin table

  if (ws_size >= 6*TB + 4*WB + TABB){
    // ---- fast path: fused prep + gload_lds GEMMs + fused-RoPE epilogue ----
    char* w = (char*)d_ws;
    u16* bQ  = (u16*)(w);                    // reused as xo after gemm_qkv_bb64
    u16* bK  = (u16*)(w + TB);
    u16* bV  = (u16*)(w + 2*TB);
    u16* bwq = (u16*)(w + 3*TB);
    u16* bwk = (u16*)(w + 3*TB + WB);
    u16* bwv = (u16*)(w + 3*TB + 2*WB);
    u16* bwo = (u16*)(w + 3*TB + 3*WB);
    u16* xq  = (u16*)(w + 3*TB + 4*WB);
    u16* xk  = (u16*)(w + 4*TB + 4*WB);
    u16* xvT = (u16*)(w + 5*TB + 4*WB);      // [b][h][d][s]
    float2* tab = (float2*)(w + 6*TB + 4*WB);
    u16* xo  = bQ;

    dim3 pg((int)(SZ/4/256), 8);             // (4096, 8)
    prep_all<<<pg, 256, 0, stream>>>(Q, K, V, wq, wk, wv, wo,
                                     bQ, bK, bV, bwq, bwk, bwv, bwo, pos, tab);

    dim3 gg(DMn/128, MR/64, 3);              // (8, 64, 3) = 1536 blocks, 6/CU
    gemm_qkv_bb64<<<gg, 256, 0, stream>>>(bQ, bK, bV, bwq, bwk, bwv, xq, xk, xvT, tab);

    attn_mfma<<<1024, 256, 0, stream>>>(xq, xk, xvT, xo);

    dim3 go(DMn/128, MR/64);                 // (8, 64) = 512 blocks, 2/CU
    gemm_out_bb64<<<go, 256, 0, stream>>>(xo, bwo, (float*)d_out);
  } else if (ws_size >= 4*TB){
    // ---- fallback: f32-input GEMMs + separate RoPE ----
    char* w = (char*)d_ws;
    u16* xq  = (u16*)(w);
    u16* xk  = (u16*)(w + TB);
    u16* xvT = (u16*)(w + 2*TB);
    u16* xo  = (u16*)(w + 3*TB);

    dim3 gg(DMn/128, MR/128, 3);
    gemm_qkv<<<gg, 256, 0, stream>>>(Q, K, V, wq, wk, wv, xq, xk, xvT);
    dim3 rg((int)(SZ/2/256), 2);
    rope2_kernel<<<rg, 256, 0, stream>>>((u32*)xq, (u32*)xk, pos);
    attn_mfma<<<1024, 256, 0, stream>>>(xq, xk, xvT, xo);
    dim3 go(DMn/128, MR/128);
    gemm_out<<<go, 256, 0, stream>>>(xo, wo, (float*)d_out);
  } else {
    hipMemsetAsync(d_out, 0x42, (size_t)out_size*4, stream);
  }
}